// Round 6
// baseline (2616.682 us; speedup 1.0000x reference)
//
#include <hip/hip_runtime.h>
#include <hip/hip_bf16.h>
#include <stdint.h>
#include <stddef.h>

#define B_  32
#define S_  400
#define T_  32
#define H_  512
#define E_  128
#define V_  50000
#define A_  512
#define H2_ 1024
#define H3_ 1536
#define H4_ 2048
#define R_  1024     // B*T
#define PGK_ 1664    // 3H+E
#define NBLKV_ 391   // ceil(V/128)
#define GRB_ 128     // persistent-recurrence grid

typedef unsigned short u16;
typedef short v8s __attribute__((ext_vector_type(8)));
typedef float v4f __attribute__((ext_vector_type(4)));

__device__ __forceinline__ float fsig(float x){ return 1.0f/(1.0f + __expf(-x)); }
__device__ __forceinline__ float ftanh(float x){ float e = __expf(2.0f*x); return 1.0f - 2.0f/(e + 1.0f); }
__device__ __forceinline__ u16 f2bf(float x){ __hip_bfloat16 b = __float2bfloat16(x); return *reinterpret_cast<u16*>(&b); }
__device__ __forceinline__ float bf2f(u16 u){ __hip_bfloat16 b = *reinterpret_cast<__hip_bfloat16*>(&u); return __bfloat162float(b); }

__device__ __forceinline__ float wsum(float v){
  #pragma unroll
  for (int off = 32; off > 0; off >>= 1) v += __shfl_xor(v, off, 64);
  return v;
}
__device__ __forceinline__ float wmax(float v){
  #pragma unroll
  for (int off = 32; off > 0; off >>= 1) v = fmaxf(v, __shfl_xor(v, off, 64));
  return v;
}

#define ALD(p)    __hip_atomic_load((p), __ATOMIC_RELAXED, __HIP_MEMORY_SCOPE_AGENT)
#define AST(p,v)  __hip_atomic_store((p), (v), __ATOMIC_RELAXED, __HIP_MEMORY_SCOPE_AGENT)

// fence-free grid barrier: monotonic count+gate; relies on __syncthreads draining
// vmcnt (compiler-guaranteed) and all cross-block data using coherent atomics.
__device__ __forceinline__ void gridbar(unsigned* bar, unsigned target){
  __syncthreads();
  if (threadIdx.x == 0){
    unsigned v = __hip_atomic_fetch_add(bar + 0, 1u, __ATOMIC_RELAXED, __HIP_MEMORY_SCOPE_AGENT);
    if (v == target*(unsigned)GRB_ - 1u){
      AST(bar + 1, target);
    } else {
      while (ALD(bar + 1) < target) __builtin_amdgcn_s_sleep(2);
    }
    asm volatile("" ::: "memory");
  }
  __syncthreads();
}

// ---------------- setup kernels ----------------

__global__ void k_init0(unsigned* __restrict__ bar){
  if (threadIdx.x < 2) AST(bar + threadIdx.x, 0u);
}

__global__ __launch_bounds__(256) void k_transpose(const float* __restrict__ in, float* __restrict__ out, int R, int C){
  __shared__ float tile[64][65];
  int c0 = blockIdx.x*64, r0 = blockIdx.y*64;
  int tid = threadIdx.x;
  int cl = tid & 63, q = tid >> 6;
  #pragma unroll
  for (int i=0;i<16;i++){
    int r = q + i*4;
    float v = 0.0f;
    if (r0 + r < R && c0 + cl < C) v = in[(size_t)(r0+r)*C + c0 + cl];
    tile[r][cl] = v;
  }
  __syncthreads();
  #pragma unroll
  for (int i=0;i<16;i++){
    int c = q + i*4;
    if (c0 + c < C && r0 + cl < R)
      out[(size_t)(c0+c)*R + r0 + cl] = tile[cl][c];
  }
}

// f32 [R][C] -> bf16 [C][R] (hi only; used for W_v)
__global__ __launch_bounds__(256) void k_convT(const float* __restrict__ in, u16* __restrict__ hi, int R, int C){
  __shared__ float tile[64][65];
  int c0 = blockIdx.x*64, r0 = blockIdx.y*64;
  int tid = threadIdx.x;
  int cl = tid & 63, q = tid >> 6;
  #pragma unroll
  for (int i=0;i<16;i++){
    int r = q + i*4;
    float v = 0.0f;
    if (r0 + r < R && c0 + cl < C) v = in[(size_t)(r0+r)*C + c0 + cl];
    tile[r][cl] = v;
  }
  __syncthreads();
  #pragma unroll
  for (int i=0;i<16;i++){
    int c = q + i*4;
    if (c0 + c < C && r0 + cl < R)
      hi[(size_t)(c0+c)*R + r0 + cl] = f2bf(tile[cl][c]);
  }
}

// W_enc [1024][512] f32 -> WencT3 [512][3072] bf16 rows = [hi | lo | hi]
__global__ __launch_bounds__(256) void k_convT3(const float* __restrict__ in, u16* __restrict__ out){
  __shared__ float tile[64][65];
  int c0 = blockIdx.x*64, r0 = blockIdx.y*64;   // grid (8,16)
  int tid = threadIdx.x;
  int cl = tid & 63, q = tid >> 6;
  #pragma unroll
  for (int i=0;i<16;i++){
    int r = q + i*4;
    tile[r][cl] = in[(size_t)(r0+r)*A_ + c0 + cl];
  }
  __syncthreads();
  #pragma unroll
  for (int i=0;i<16;i++){
    int c = q + i*4;
    float v = tile[cl][c];
    u16 h = f2bf(v);
    u16 lo = f2bf(v - bf2f(h));
    size_t o = (size_t)(c0+c)*3072 + (r0+cl);
    out[o] = h;
    out[o + 1024] = lo;
    out[o + 2048] = h;
  }
}

// enc [12800][1024] f32 -> enc3 [12800][3072] bf16 rows = [hi | hi | lo]
__global__ void k_conv3(const float* __restrict__ in, u16* __restrict__ out, int n4){
  int i = blockIdx.x*256 + threadIdx.x;
  if (i >= n4) return;
  float4 x = reinterpret_cast<const float4*>(in)[i];
  u16 h0v=f2bf(x.x), h1v=f2bf(x.y), h2v=f2bf(x.z), h3v=f2bf(x.w);
  uint2 hv; hv.x = (unsigned)h0v | ((unsigned)h1v << 16); hv.y = (unsigned)h2v | ((unsigned)h3v << 16);
  uint2 lv;
  lv.x = (unsigned)f2bf(x.x - bf2f(h0v)) | ((unsigned)f2bf(x.y - bf2f(h1v)) << 16);
  lv.y = (unsigned)f2bf(x.z - bf2f(h2v)) | ((unsigned)f2bf(x.w - bf2f(h3v)) << 16);
  int row = i >> 8, c = (i & 255)*4;
  size_t base = (size_t)row*3072 + c;
  *reinterpret_cast<uint2*>(out + base)        = hv;
  *reinterpret_cast<uint2*>(out + base + 1024) = hv;
  *reinterpret_cast<uint2*>(out + base + 2048) = lv;
}

// G2[t][g][hidx][b] = b_ih + b_hh + emb @ W_ih^T   (layout for k_recur coalesced reads)
__global__ __launch_bounds__(256) void k_gih(const float* __restrict__ emb, const float* __restrict__ WihT,
    const float* __restrict__ b_ih, const float* __restrict__ b_hh, float* __restrict__ G){
  __shared__ float em[8][128];
  int r0 = blockIdx.x*8;
  int tid = threadIdx.x;
  #pragma unroll
  for (int i=0;i<4;i++){
    int e = i*256 + tid;
    em[e>>7][e&127] = emb[(size_t)(r0 + (e>>7))*E_ + (e&127)];
  }
  __syncthreads();
  for (int jj=0;jj<8;jj++){
    int j = jj*256 + tid;
    float bias = b_ih[j] + b_hh[j];
    float acc[8];
    #pragma unroll
    for (int r=0;r<8;r++) acc[r] = bias;
    for (int e=0;e<128;e++){
      float wv = WihT[(size_t)e*H4_ + j];
      #pragma unroll
      for (int r=0;r<8;r++) acc[r] += em[r][e]*wv;
    }
    #pragma unroll
    for (int rr=0;rr<8;rr++){
      int r = r0 + rr;
      G[(size_t)(r & 31)*65536 + (size_t)(j >> 9)*16384 + (size_t)(j & 511)*32 + (r >> 5)] = acc[rr];
    }
  }
}

// ---------------- MFMA bf16 GEMM (coalesced LDS epilogue, optional stats) ----------------
__global__ __launch_bounds__(256, 2) void k_gemm_bf16(
    const u16* __restrict__ A, int lda, const u16* __restrict__ Bt, int ldb,
    const float* __restrict__ bias, float* __restrict__ Cf, u16* __restrict__ Cbf, int ldc,
    int M, int N, int K, float2* __restrict__ stats, int nblk)
{
  __shared__ __align__(16) float CsF[128*132];
  __shared__ float rs[128], rs2[128];
  u16* As = reinterpret_cast<u16*>(CsF);
  u16* Bs = As + 128*64;
  const int tid = threadIdx.x;
  const int m0 = blockIdx.y * 128;
  const int n0 = blockIdx.x * 128;
  const int l  = tid & 63;
  const int wavebase = tid & ~63;
  const int wid = tid >> 6;
  const int wm = (wid >> 1) * 64;
  const int wn = (wid & 1) * 64;

  v4f acc[4][4];
  v4f vzero = {0.0f, 0.0f, 0.0f, 0.0f};
  #pragma unroll
  for (int i=0;i<4;i++)
    #pragma unroll
    for (int j=0;j<4;j++) acc[i][j] = vzero;

  for (int k0 = 0; k0 < K; k0 += 64){
    __syncthreads();
    #pragma unroll
    for (int jj=0;jj<4;jj++){
      int fc = jj*256 + tid;
      int row = fc >> 3;
      int cc = (fc & 7) ^ (row & 7);
      const u16* g = A + (size_t)(m0 + row)*lda + k0 + cc*8;
      __builtin_amdgcn_global_load_lds(
        (__attribute__((address_space(1))) void*)g,
        (__attribute__((address_space(3))) void*)(As + (size_t)(jj*256 + wavebase)*8),
        16, 0, 0);
    }
    #pragma unroll
    for (int jj=0;jj<4;jj++){
      int fc = jj*256 + tid;
      int row = fc >> 3;
      int cc = (fc & 7) ^ (row & 7);
      int rn = n0 + row; if (rn > N-1) rn = N-1;
      const u16* g = Bt + (size_t)rn*ldb + k0 + cc*8;
      __builtin_amdgcn_global_load_lds(
        (__attribute__((address_space(1))) void*)g,
        (__attribute__((address_space(3))) void*)(Bs + (size_t)(jj*256 + wavebase)*8),
        16, 0, 0);
    }
    __syncthreads();
    #pragma unroll
    for (int ks=0;ks<2;ks++){
      v8s af[4], bfr[4];
      #pragma unroll
      for (int rt=0;rt<4;rt++){
        int r = wm + rt*16 + (l & 15);
        int cs = (ks*4 + (l >> 4)) ^ (r & 7);
        af[rt] = *reinterpret_cast<const v8s*>(As + r*64 + cs*8);
      }
      #pragma unroll
      for (int nt=0;nt<4;nt++){
        int r = wn + nt*16 + (l & 15);
        int cs = (ks*4 + (l >> 4)) ^ (r & 7);
        bfr[nt] = *reinterpret_cast<const v8s*>(Bs + r*64 + cs*8);
      }
      #pragma unroll
      for (int rt=0;rt<4;rt++)
        #pragma unroll
        for (int nt=0;nt<4;nt++)
          acc[rt][nt] = __builtin_amdgcn_mfma_f32_16x16x32_bf16(af[rt], bfr[nt], acc[rt][nt], 0, 0, 0);
    }
  }

  const int cl = l & 15;
  const int rg = (l >> 4) * 4;
  float cvv[4][4][4];
  #pragma unroll
  for (int rt=0;rt<4;rt++)
    #pragma unroll
    for (int nt=0;nt<4;nt++){
      int gc = n0 + wn + nt*16 + cl;
      float bv = (bias && gc < N) ? bias[gc] : 0.0f;
      #pragma unroll
      for (int i=0;i<4;i++) cvv[rt][nt][i] = acc[rt][nt][i] + bv;
    }

  if (stats){
    float tsm[4][4];
    #pragma unroll
    for (int rt=0;rt<4;rt++)
      #pragma unroll
      for (int i=0;i<4;i++){
        float mx = -1e30f;
        #pragma unroll
        for (int nt=0;nt<4;nt++){
          int gc = n0 + wn + nt*16 + cl;
          if (gc < N) mx = fmaxf(mx, cvv[rt][nt][i]);
        }
        #pragma unroll
        for (int off=1; off<16; off<<=1) mx = fmaxf(mx, __shfl_xor(mx, off, 64));
        if (wn == 0 && cl == 0) rs[wm + rt*16 + rg + i] = mx;
        tsm[rt][i] = mx;
      }
    __syncthreads();
    if (wn != 0){
      #pragma unroll
      for (int rt=0;rt<4;rt++)
        #pragma unroll
        for (int i=0;i<4;i++){
          float c = fmaxf(tsm[rt][i], rs[wm + rt*16 + rg + i]);
          if (cl == 0) rs[wm + rt*16 + rg + i] = c;
        }
    }
    __syncthreads();
    #pragma unroll
    for (int rt=0;rt<4;rt++)
      #pragma unroll
      for (int i=0;i<4;i++){
        float rm = rs[wm + rt*16 + rg + i];
        float sm = 0.0f;
        #pragma unroll
        for (int nt=0;nt<4;nt++){
          int gc = n0 + wn + nt*16 + cl;
          if (gc < N) sm += __expf(cvv[rt][nt][i] - rm);
        }
        #pragma unroll
        for (int off=1; off<16; off<<=1) sm += __shfl_xor(sm, off, 64);
        tsm[rt][i] = sm;
        if (wn == 0 && cl == 0) rs2[wm + rt*16 + rg + i] = sm;
      }
    __syncthreads();
    if (wn != 0 && cl == 0){
      #pragma unroll
      for (int rt=0;rt<4;rt++)
        #pragma unroll
        for (int i=0;i<4;i++){
          int row = wm + rt*16 + rg + i;
          stats[(size_t)(m0 + row)*nblk + blockIdx.x] =
            make_float2(rs[row], tsm[rt][i] + rs2[row]);
        }
    }
  }

  __syncthreads();
  #pragma unroll
  for (int rt=0;rt<4;rt++)
    #pragma unroll
    for (int nt=0;nt<4;nt++)
      #pragma unroll
      for (int i=0;i<4;i++)
        CsF[(wm + rt*16 + rg + i)*132 + wn + nt*16 + cl] = cvv[rt][nt][i];
  __syncthreads();
  #pragma unroll
  for (int it=0; it<16; ++it){
    int row = (tid >> 5) + it*8;
    int c4 = tid & 31;
    int gc = n0 + c4*4;
    int gr = m0 + row;
    if (gc < N){
      float4 v = *reinterpret_cast<const float4*>(&CsF[row*132 + c4*4]);
      if (Cf) *reinterpret_cast<float4*>(Cf + (size_t)gr*ldc + gc) = v;
      if (Cbf){
        uint2 o;
        o.x = (unsigned)f2bf(v.x) | ((unsigned)f2bf(v.y) << 16);
        o.y = (unsigned)f2bf(v.z) | ((unsigned)f2bf(v.w) << 16);
        *reinterpret_cast<uint2*>(Cbf + (size_t)gr*ldc + gc) = o;
      }
    }
  }
}

// fallback f32 GEMM for W_v when ws too small
__global__ __launch_bounds__(256) void k_wv_f32(
  const float* __restrict__ Aah, const float* __restrict__ Wv, const float* __restrict__ bv,
  float* __restrict__ Cl)
{
  __shared__ float Asf[32][68];
  __shared__ float Bsf[32][64];
  int n0 = blockIdx.x*64, m0 = blockIdx.y*64;
  int tid = threadIdx.x;
  int tx = tid & 15, ty = tid >> 4;
  float acc[4][4] = {};
  for (int kc = 0; kc < H_; kc += 32){
    __syncthreads();
    #pragma unroll
    for (int i=0;i<8;i++){
      int e = i*256 + tid;
      Asf[e & 31][e >> 5] = Aah[(size_t)(m0 + (e >> 5))*H_ + kc + (e & 31)];
    }
    #pragma unroll
    for (int i=0;i<8;i++){
      int e = i*256 + tid;
      int nc = n0 + (e & 63); if (nc >= V_) nc = V_-1;
      Bsf[e >> 6][e & 63] = Wv[(size_t)(kc + (e >> 6))*V_ + nc];
    }
    __syncthreads();
    #pragma unroll
    for (int k=0;k<32;k++){
      float4 a4 = *reinterpret_cast<const float4*>(&Asf[k][ty*4]);
      float4 b4 = *reinterpret_cast<const float4*>(&Bsf[k][tx*4]);
      float av[4] = {a4.x, a4.y, a4.z, a4.w};
      float bv4[4] = {b4.x, b4.y, b4.z, b4.w};
      #pragma unroll
      for (int i=0;i<4;i++)
        #pragma unroll
        for (int j=0;j<4;j++)
          acc[i][j] = __builtin_fmaf(av[i], bv4[j], acc[i][j]);
    }
  }
  #pragma unroll
  for (int i=0;i<4;i++){
    int rr = m0 + ty*4 + i;
    #pragma unroll
    for (int j=0;j<4;j++){
      int cc = n0 + tx*4 + j;
      if (cc < V_) Cl[(size_t)rr*V_ + cc] = acc[i][j] + bv[cc];
    }
  }
}

// ---------------- persistent fused recurrence (ONE barrier/step) ----------------
// iter i: X = [stage h_i (coalesced coherent); dec_{i-1} slice; gates_i (W in LDS);
//              publish h_{i+1}, dec] -> gridbar -> Y = [read dec full; ALL 400 scores
//              (4x redundant per batch group, XCD-local); block-local softmax;
//              attn/cov (role 0 writes)].  No mz exchange, 33 barriers total.
__global__ __launch_bounds__(512, 1) void k_recur(
  const float* __restrict__ W_hh, const float* __restrict__ G2,
  const float* __restrict__ W_decT, const u16* __restrict__ ep_bf,
  const float* __restrict__ w_cov, const float* __restrict__ v_att,
  const void* __restrict__ maskp, const float* __restrict__ h0,
  const float* __restrict__ c0, float* __restrict__ h_gT,
  float* __restrict__ dec_g,
  float* __restrict__ catbuf, float* __restrict__ attns, float* __restrict__ covs,
  unsigned* __restrict__ bar)
{
  const int beta = blockIdx.x;
  const int tid = threadIdx.x;
  __shared__ float h_lds[512*33];      // 67.6 KB, [k][b] padded
  __shared__ float W_l[16][512];       // 32 KB: this block's 16 W_hh rows
  __shared__ float Wd_l[4][512];       // 8 KB: this block's 4 W_decT rows
  __shared__ float gv[4][4][32];
  __shared__ float pdec[4][4][32];
  __shared__ float c_l[128];
  __shared__ float dec_l[512];
  __shared__ float sc_l[400];
  __shared__ float cov_l[400];
  __shared__ float red[16];

  const int b32 = tid & 31;
  const int hl  = (tid >> 5) & 3;
  const int g   = tid >> 7;           // gate id; also k-quarter for dec
  const int w = tid >> 6, l = tid & 63;
  // Y-phase mapping: keep a batch's 4 blocks on one XCD (assumes xcd = blockIdx%8)
  const int bb = (beta & 7)*4 + ((beta >> 3) & 3);
  const int sq = beta >> 5;           // role 0..3; role 0 writes outputs

  // one-time staging (reused across all 32 steps)
  for (int idx = tid; idx < 16*512; idx += 512){
    int row = idx >> 9;               // row = g*4 + hl
    int k = idx & 511;
    W_l[row][k] = W_hh[((size_t)(row >> 2)*H_ + beta*4 + (row & 3))*H_ + k];
  }
  for (int idx = tid; idx < 4*512; idx += 512)
    Wd_l[idx >> 9][idx & 511] = W_decT[(size_t)(beta*4 + (idx >> 9))*H_ + (idx & 511)];
  if (tid < 128) c_l[tid] = c0[(size_t)(tid & 31)*H_ + beta*4 + (tid >> 5)];
  if (tid < 400) cov_l[tid] = 0.f;

  const unsigned* m32p = (const unsigned*)maskp;
  const unsigned char* m8p = (const unsigned char*)maskp;
  const bool bytemode = (m32p[0] == 0x01010101u);

  float wc8[8], va8[8];
  {
    int a0 = l*8;
    #pragma unroll
    for (int j=0;j<8;j++){ wc8[j] = w_cov[a0+j]; va8[j] = v_att[a0+j]; }
  }

  unsigned gen = 0;
  for (int i = 0; i <= T_; ++i){
    // ---- X: stage h_i into LDS (coalesced) ----
    if (i == 0){
      #pragma unroll
      for (int j=0;j<32;j++){
        int flat = j*512 + tid;              // h0 layout [b][k]
        h_lds[(flat & 511)*33 + (flat >> 9)] = h0[flat];
      }
    } else {
      const float* hp = h_gT + (size_t)(i & 1)*16384;   // layout [k][b]
      #pragma unroll
      for (int j=0;j<32;j++){
        int flat = j*512 + tid;
        h_lds[(flat >> 5)*33 + (flat & 31)] = ALD(hp + flat);
      }
    }
    __syncthreads();

    // ---- dec_{i-1}: a = beta*4+hl, k-quarter g ----
    if (i > 0){
      float acc = 0.f;
      const float* Wr = &Wd_l[hl][g*128];
      const int kq = g*128;
      #pragma unroll 8
      for (int k=0;k<128;k++)
        acc = __builtin_fmaf(h_lds[(kq + k)*33 + b32], Wr[k], acc);
      pdec[g][hl][b32] = acc;
    }
    // ---- gates_i: full-K dot ----
    if (i < T_){
      const float* Wr = &W_l[g*4 + hl][0];
      float x0=0.f, x1=0.f, x2=0.f, x3=0.f;
      #pragma unroll 8
      for (int k=0;k<128;k++){
        x0 = __builtin_fmaf(h_lds[(k      )*33 + b32], Wr[k      ], x0);
        x1 = __builtin_fmaf(h_lds[(k + 128)*33 + b32], Wr[k + 128], x1);
        x2 = __builtin_fmaf(h_lds[(k + 256)*33 + b32], Wr[k + 256], x2);
        x3 = __builtin_fmaf(h_lds[(k + 384)*33 + b32], Wr[k + 384], x3);
      }
      gv[g][hl][b32] = (x0 + x1) + (x2 + x3);
    }
    __syncthreads();

    if (i > 0 && tid < 128){
      int al = tid >> 5;
      float d = pdec[0][al][b32] + pdec[1][al][b32] + pdec[2][al][b32] + pdec[3][al][b32];
      AST(dec_g + (size_t)b32*A_ + beta*4 + al, d);
    }
    if (i < T_ && tid < 128){
      int hh = tid >> 5;
      int hidx = beta*4 + hh;
      const float* Gr = G2 + (size_t)i*65536 + (size_t)hidx*32 + b32;
      float gi = gv[0][hh][b32] + Gr[0];
      float gf = gv[1][hh][b32] + Gr[16384];
      float gg = gv[2][hh][b32] + Gr[32768];
      float go = gv[3][hh][b32] + Gr[49152];
      float co = c_l[tid];
      float cn = fsig(gf)*co + fsig(gi)*ftanh(gg);
      float hn = fsig(go)*ftanh(cn);
      c_l[tid] = cn;
      AST(h_gT + (size_t)((i & 1)^1)*16384 + (size_t)hidx*32 + b32, hn);
      catbuf[(size_t)(b32*T_ + i)*H3_ + H2_ + hidx] = hn;
    }
    gridbar(bar, ++gen);

    // ---- Y: scores_{i-1}, full 400 per block (4x redundant), local softmax ----
    if (i > 0){
      const int step = i - 1;
      const int r = bb*T_ + step;
      dec_l[tid] = ALD(dec_g + (size_t)bb*A_ + tid);
      __syncthreads();
      int a0 = l*8;
      float dec8[8];
      #pragma unroll
      for (int j=0;j<8;j++) dec8[j] = dec_l[a0+j];
      for (int it=0; it<50; ++it){
        int s = w + it*8;                  // 8 warps x 50 = 400
        float cv = cov_l[s];
        uint4 e8 = *reinterpret_cast<const uint4*>(ep_bf + (size_t)(bb*S_ + s)*A_ + a0);
        unsigned uu[4] = {e8.x, e8.y, e8.z, e8.w};
        float part = 0.f;
        #pragma unroll
        for (int j=0;j<4;j++){
          float xa = bf2f((u16)(uu[j] & 0xFFFFu)) + dec8[2*j]   + cv*wc8[2*j];
          part += va8[2*j]*ftanh(xa);
          float xb = bf2f((u16)(uu[j] >> 16))     + dec8[2*j+1] + cv*wc8[2*j+1];
          part += va8[2*j+1]*ftanh(xb);
        }
        part = wsum(part);
        if (l == 0){
          bool on = bytemode ? (m8p[bb*S_+s] != 0) : (m32p[bb*S_+s] != 0u);
          sc_l[s] = on ? part : -1e9f;
        }
      }
      __syncthreads();
      // block softmax over 400
      float x = (tid < 400) ? sc_l[tid] : -1e30f;
      float m = wmax(x);
      if (l == 0) red[w] = m;
      __syncthreads();
      float gm = red[0];
      #pragma unroll
      for (int j=1;j<8;j++) gm = fmaxf(gm, red[j]);
      float z = (tid < 400) ? __expf(x - gm) : 0.f;
      float zs = wsum(z);
      if (l == 0) red[8 + w] = zs;
      __syncthreads();
      float gZ = red[8];
      #pragma unroll
      for (int j=9;j<16;j++) gZ += red[j];
      float invZ = 1.f/gZ;
      if (tid < 400){
        float av = z*invZ;
        float cn = cov_l[tid] + av;
        cov_l[tid] = cn;
        if (sq == 0){
          attns[(size_t)r*S_ + tid] = av;
          covs[(size_t)r*S_ + tid]  = cn;
        }
      }
      __syncthreads();
    }
  }
}

// ---------------- post-loop kernels ----------------

// context (deferred): catbuf[:, :1024] = attns @ enc   (fp32, single enc pass)
__global__ __launch_bounds__(256, 2) void k_ctx(
  const float* __restrict__ attns, const float* __restrict__ enc, float* __restrict__ catbuf)
{
  __shared__ float att_s[32][400];
  int d0 = blockIdx.x*64, b = blockIdx.y;
  int tid = threadIdx.x;
  for (int tt=0; tt<32; ++tt)
    for (int s = tid; s < S_; s += 256)
      att_s[tt][s] = attns[(size_t)(b*T_ + tt)*S_ + s];
  __syncthreads();
  int d = d0 + (tid & 63);
  int t0 = (tid >> 6)*8;
  float acc[8] = {0,0,0,0,0,0,0,0};
  const float* encb = enc + (size_t)b*S_*H2_ + d;
  #pragma unroll 4
  for (int s=0; s<S_; ++s){
    float ev = encb[(size_t)s*H2_];
    #pragma unroll
    for (int i=0;i<8;i++) acc[i] = __builtin_fmaf(att_s[t0+i][s], ev, acc[i]);
  }
  #pragma unroll
  for (int i=0;i<8;i++)
    catbuf[(size_t)(b*T_ + t0 + i)*H3_ + d] = acc[i];
}

// fp32 tiled GEMM: dec_states = tanh(catbuf @ W_ah + b_ah); optional bf16 copy
__global__ __launch_bounds__(256) void k_ahgemm(
  const float* __restrict__ Acat, const float* __restrict__ W_ah, const float* __restrict__ b_ah,
  float* __restrict__ dec_states, u16* __restrict__ ah_bf)
{
  __shared__ float Asf[32][68];
  __shared__ float Bsf[32][64];
  int n0 = blockIdx.x*64, m0 = blockIdx.y*64;
  int tid = threadIdx.x;
  int tx = tid & 15, ty = tid >> 4;
  float acc[4][4] = {};
  for (int kc = 0; kc < H3_; kc += 32){
    __syncthreads();
    #pragma unroll
    for (int i=0;i<8;i++){
      int e = i*256 + tid;
      Asf[e & 31][e >> 5] = Acat[(size_t)(m0 + (e >> 5))*H3_ + kc + (e & 31)];
    }
    #pragma unroll
    for (int i=0;i<8;i++){
      int e = i*256 + tid;
      Bsf[e >> 6][e & 63] = W_ah[(size_t)(kc + (e >> 6))*H_ + n0 + (e & 63)];
    }
    __syncthreads();
    #pragma unroll
    for (int k=0;k<32;k++){
      float4 a4 = *reinterpret_cast<const float4*>(&Asf[k][ty*4]);
      float4 b4 = *reinterpret_cast<const float4*>(&Bsf[k][tx*4]);
      float av[4] = {a4.x, a4.y, a4.z, a4.w};
      float bv[4] = {b4.x, b4.y, b4.z, b4.w};
      #pragma unroll
      for (int i=0;i<4;i++)
        #pragma unroll
        for (int j=0;j<4;j++)
          acc[i][j] = __builtin_fmaf(av[i], bv[j], acc[i][j]);
    }
  }
  #pragma unroll
  for (int i=0;i<4;i++){
    int rr = m0 + ty*4 + i;
    #pragma unroll
    for (int j=0;j<4;j++){
      int cc = n0 + tx*4 + j;
      float v = ftanh(acc[i][j] + b_ah[cc]);
      dec_states[(size_t)rr*H_ + cc] = v;
      if (ah_bf) ah_bf[(size_t)rr*H_ + cc] = f2bf(v);
    }
  }
}

__global__ __launch_bounds__(512) void k_pgen(const float* __restrict__ catbuf, const float* __restrict__ emb,
  const float* __restrict__ W_pg, const float* __restrict__ b_pg, float* __restrict__ pgens)
{
  int w = threadIdx.x >> 6, l = threadIdx.x & 63;
  int r = blockIdx.x*8 + w;
  float part = 0.0f;
  for (int d = l; d < PGK_; d += 64){
    float x = (d < H3_) ? catbuf[(size_t)r*H3_ + d] : emb[(size_t)r*E_ + (d - H3_)];
    part += x*W_pg[d];
  }
  part = wsum(part);
  if (l == 0) pgens[r] = fsig(part + b_pg[0]);
}

// per-row final: stats merge -> bitmask+hash scatter -> fast log transform
__global__ __launch_bounds__(512) void k_final2(
  float* __restrict__ logits, const float* __restrict__ pgens,
  const float* __restrict__ attns, const int* __restrict__ src,
  const float2* __restrict__ stats, int nblk)
{
  __shared__ unsigned bits[1568];
  __shared__ unsigned keys[1024];
  __shared__ float vals[1024];
  __shared__ float sred[18];
  int r = blockIdx.x;
  int b = r >> 5;
  int tid = threadIdx.x;
  int w = tid >> 6, l = tid & 63;
  float* row = logits + (size_t)r*V_;

  for (int i = tid; i < 1568; i += 512) bits[i] = 0u;
  for (int i = tid; i < 1024; i += 512){ keys[i] = 0xFFFFFFFFu; vals[i] = 0.0f; }

  if (stats){
    float m = -1e30f, Z = 0.0f;
    if (tid < nblk){ float2 st = stats[(size_t)r*nblk + tid]; m = st.x; Z = st.y; }
    #pragma unroll
    for (int off=32; off>0; off>>=1){
      float mo = __shfl_xor(m, off, 64);
      float Zo = __shfl_xor(Z, off, 64);
      float nm = fmaxf(m, mo);
      Z = Z*__expf(m - nm) + Zo*__expf(mo - nm);
      m = nm;
    }
    if (l == 0){ sred[w*2] = m; sred[w*2+1] = Z; }
    __syncthreads();
    if (tid == 0){
      float gm = -1e30f, gz = 0.0f;
      #pragma unroll
      for (int i=0;i<8;i++){
        float mi = sred[i*2], zi = sred[i*2+1];
        float nm = fmaxf(gm, mi);
        gz = gz*__expf(gm - nm) + zi*__expf(mi - nm);
        gm = nm;
      }
      sred[16] = gm; sred[17] = gz;
    }
    __syncthreads();
  } else {
    float m = -1e30f;
    for (int j = tid; j < V_/4; j += 512){
      float4 x = reinterpret_cast<const float4*>(row)[j];
      m = fmaxf(fmaxf(m, x.x), fmaxf(fmaxf(x.y, x.z), x.w));
    }
    m = wmax(m);
    if (l == 0) sred[w] = m;
    __syncthreads();
    if (tid == 0){
      float gm = -1e30f;
      #pragma unroll
      for (int i=0;i<8;i++) gm = fmaxf(gm, sred[i]);
      sred[16] = gm;
    }
    __syncthreads();
    float gm = sred[16];
    float z = 0.0f;
    for (int j = tid; j < V_/4; j += 512){
      float4 x = reinterpret_cast<const float4*>(row)[j];
      z += __expf(x.x-gm) + __expf(x.y-gm) + __expf(x.z-gm) + __expf(x.w-gm);
    }
    z = wsum(z);
    if (l == 0) sred[8 + w] = z;
    __syncthreads();
    if (tid == 0){
      float gz = 0.0f;
      #pragma unroll
      for (int i=0;i<8;i++) gz += sred[8 + i];
      sred[17] = gz;
    }
    __syncthreads();
  }

  float gm = sred[16];
  float gZ = sred[17];
  float pg = pgens[r];
  float scale = pg / gZ;
  float lscale = __logf(scale);

  if (tid < S_){
    int tok = src[b*S_ + tid];
    float add = (1.0f - pg)*attns[(size_t)r*S_ + tid];
    atomicOr(&bits[tok >> 5], 1u << (tok & 31));
    unsigned h = ((unsigned)tok * 2654435761u) >> 22;
    while (true){
      unsigned prev = atomicCAS(&keys[h], 0xFFFFFFFFu, (unsigned)tok);
      if (prev == 0xFFFFFFFFu || prev == (unsigned)tok){
        atomicAdd(&vals[h], add);
        break;
      }
      h = (h + 1) & 1023;
    }
  }
  __syncthreads();

  for (int j = tid; j < V_/4; j += 512){
    float4 x = reinterpret_cast<const float4*>(row)[j];
    int v = 4*j;
    float o[4];
    float xv[4] = {x.x, x.y, x.z, x.w};
    #pragma unroll
    for (int k=0;k<4;k++){
      int vv = v + k;
      bool hit = (bits[vv >> 5] >> (vv & 31)) & 1u;
      float tt = xv[k] - gm + lscale;
      if (!hit && tt > -25.0f){
        o[k] = tt;
      } else {
        float pval = __expf(xv[k] - gm)*scale;
        if (hit){
          unsigned h = ((unsigned)vv * 2654435761u) >> 22;
          while (keys[h] != 0xFFFFFFFFu){
            if (keys[h] == (unsigned)vv){ pval += vals[h]; break; }
            h = (h + 1) & 1023;
          }
        }
        o[k] = __logf(pval + 1e-20f);
      }
    }
    reinterpret_cast<float4*>(row)[j] = make_float4(o[0], o[1], o[2], o[3]);
  }
}

// ---------------- host ----------------

extern "C" void kernel_launch(void* const* d_in, const int* in_sizes, int n_in,
                              void* d_out, int out_size, void* d_ws, size_t ws_size,
                              hipStream_t stream)
{
  const int* src_tokens = (const int*)d_in[0];
  const float* embedded = (const float*)d_in[1];
  const float* enc      = (const float*)d_in[2];
  const void*  maskp    = (const void*)d_in[3];
  const float* h0  = (const float*)d_in[4];
  const float* c0  = (const float*)d_in[5];
  const float* W_ih = (const float*)d_in[6];
  const float* W_hh = (const float*)d_in[7];
  const float* b_ih = (const float*)d_in[8];
  const float* b_hh = (const float*)d_in[9];
  const float* W_enc = (const float*)d_in[10];
  const float* W_dec = (const float*)d_in[11];
  const float* w_cov = (const float*)d_in[12];
  const float* b_att = (const float*)d_in[13];
  const float* v_att = (const float*)d_in[14];
  const float* W_ah  = (const float*)d_in[15];
  const float* b_ah  = (const float*)d_in[16];
  const float* W_pg  = (const float*)d_in[17];
  const float* b_pg  = (const float*)d_in[18];
  const float* W_v   = (const float*)d_in[19];
  const float* b_v   = (const float*)d_in[20];
  (void)in_sizes; (void)n_in; (void)out_size;

  float* outp = (float*)d_out;
  float* logps = outp;                                  // (B,T,V)   204.8 MB
  float* dec_states = logps + (size_t)R_*V_;            // (B,T,H)
  float* attns = dec_states + (size_t)R_*H_;            // (B,T,S)
  float* covs  = attns + (size_t)R_*S_;                 // (B,T,S)
  float* pgens = covs + (size_t)R_*S_;                  // (B,T)

  // big transients live INSIDE the logps output region (dead until W_v GEMM)
  char* sp = (char*)logps;
  auto salloc = [&](size_t bytes) -> void* {
    void* p = (void*)sp;
    sp += (bytes + 255) & ~(size_t)255;
    return p;
  };
  unsigned* bar = (unsigned*)salloc(256);
  u16* ep_bf    = (u16*)salloc((size_t)B_*S_*A_*2);        // 13.1 MB
  u16* enc3     = (u16*)salloc((size_t)B_*S_*3072*2);      // 78.6 MB
  u16* WencT3   = (u16*)salloc((size_t)A_*3072*2);         // 3.1 MB
  float* WihT   = (float*)salloc((size_t)E_*H4_*4);        // 1 MB
  float* W_decT = (float*)salloc((size_t)H_*A_*4);         // 1 MB
  float* G2     = (float*)salloc((size_t)R_*H4_*4);        // 8.4 MB [t][g][hidx][b]
  float* catbuf = (float*)salloc((size_t)R_*H3_*4);        // 6.3 MB [context | h]
  float* dec_g  = (float*)salloc((size_t)B_*A_*4);         // 64 KB
  float* h_gT   = (float*)salloc((size_t)2*H_*B_*4);       // 128 KB double-buffered [k][b]
  // total ~112 MB < 204.8 MB -- all consumed before W_v GEMM writes logps

  // d_ws: only buffers live WHILE logps is being written
  char* wp = (char*)d_ws;
  auto walloc = [&](size_t bytes) -> void* {
    void* p = (void*)wp;
    wp += (bytes + 255) & ~(size_t)255;
    return p;
  };
  u16* ah_bf = (u16*)walloc((size_t)R_*H_*2);              // 1.05 MB
  u16* WvT   = (u16*)walloc((size_t)V_*H_*2);              // 51.2 MB
  float2* stats = (float2*)walloc((size_t)R_*NBLKV_*8);    // 3.2 MB
  const size_t ws_fast  = (size_t)R_*H_*2 + (size_t)V_*H_*2 + 512;
  const size_t ws_stats = ws_fast + (size_t)R_*NBLKV_*8 + 256;
  const bool fast_wv   = (ws_size >= ws_fast);
  const bool use_stats = (ws_size >= ws_stats);

  // setup
  k_init0<<<1, 64, 0, stream>>>(bar);
  k_transpose<<<dim3(2,32), 256, 0, stream>>>(W_ih, WihT, H4_, E_);
  k_transpose<<<dim3(8,8), 256, 0, stream>>>(W_dec, W_decT, H_, A_);
  k_gih<<<128, 256, 0, stream>>>(embedded, WihT, b_ih, b_hh, G2);
  k_conv3<<<(B_*S_*H2_/4 + 255)/256, 256, 0, stream>>>(enc, enc3, B_*S_*H2_/4);
  k_convT3<<<dim3(8,16), 256, 0, stream>>>(W_enc, WencT3);
  if (fast_wv)
    k_convT<<<dim3((V_+63)/64, 8), 256, 0, stream>>>(W_v, WvT, H_, V_);

  // enc_proj: single split-bf16 GEMM (K=3072), bf16 output + b_att
  k_gemm_bf16<<<dim3(A_/128, (B_*S_)/128), 256, 0, stream>>>(
      enc3, 3072, WencT3, 3072, b_att, nullptr, ep_bf, A_, B_*S_, A_, 3072, nullptr, 0);

  // fused persistent recurrence (one barrier per step)
  k_recur<<<GRB_, 512, 0, stream>>>(W_hh, G2, W_decT, ep_bf, w_cov, v_att, maskp,
                                    h0, c0, h_gT, dec_g,
                                    catbuf, attns, covs, bar);

  // deferred contexts + batched tail
  k_ctx<<<dim3(16, 32), 256, 0, stream>>>(attns, enc, catbuf);
  k_ahgemm<<<dim3(8,16), 256, 0, stream>>>(catbuf, W_ah, b_ah, dec_states, fast_wv ? ah_bf : (u16*)nullptr);
  k_pgen<<<128, 512, 0, stream>>>(catbuf, embedded, W_pg, b_pg, pgens);

  // logits
  if (fast_wv)
    k_gemm_bf16<<<dim3(NBLKV_, R_/128), 256, 0, stream>>>(
        ah_bf, H_, WvT, H_, b_v, logps, nullptr, V_, R_, V_, H_,
        use_stats ? stats : nullptr, NBLKV_);
  else
    k_wv_f32<<<dim3((V_+63)/64, R_/64), 256, 0, stream>>>(dec_states, W_v, b_v, logps);

  k_final2<<<R_, 512, 0, stream>>>(logps, pgens, attns, src_tokens,
                                   (fast_wv && use_stats) ? stats : nullptr, NBLKV_);
}

// Round 7
// 1725.679 us; speedup vs baseline: 1.5163x; 1.5163x over previous
//
#include <hip/hip_runtime.h>
#include <hip/hip_bf16.h>
#include <stdint.h>
#include <stddef.h>

#define B_  32
#define S_  400
#define T_  32
#define H_  512
#define E_  128
#define V_  50000
#define A_  512
#define H2_ 1024
#define H3_ 1536
#define H4_ 2048
#define R_  1024     // B*T
#define PGK_ 1664    // 3H+E
#define NBLKV_ 391   // ceil(V/128)
#define GRB_ 128     // persistent-recurrence grid

typedef unsigned short u16;
typedef short v8s __attribute__((ext_vector_type(8)));
typedef float v4f __attribute__((ext_vector_type(4)));

__device__ __forceinline__ float fsig(float x){ return 1.0f/(1.0f + __expf(-x)); }
__device__ __forceinline__ float ftanh(float x){ float e = __expf(2.0f*x); return 1.0f - 2.0f/(e + 1.0f); }
__device__ __forceinline__ u16 f2bf(float x){ __hip_bfloat16 b = __float2bfloat16(x); return *reinterpret_cast<u16*>(&b); }
__device__ __forceinline__ float bf2f(u16 u){ __hip_bfloat16 b = *reinterpret_cast<__hip_bfloat16*>(&u); return __bfloat162float(b); }

__device__ __forceinline__ float wsum(float v){
  #pragma unroll
  for (int off = 32; off > 0; off >>= 1) v += __shfl_xor(v, off, 64);
  return v;
}
__device__ __forceinline__ float wmax(float v){
  #pragma unroll
  for (int off = 32; off > 0; off >>= 1) v = fmaxf(v, __shfl_xor(v, off, 64));
  return v;
}

#define ALD(p)    __hip_atomic_load((p), __ATOMIC_RELAXED, __HIP_MEMORY_SCOPE_AGENT)
#define AST(p,v)  __hip_atomic_store((p), (v), __ATOMIC_RELAXED, __HIP_MEMORY_SCOPE_AGENT)

// hierarchical fence-free grid barrier: 8 spread counters (16 arrivals each,
// keyed by beta&7) -> 1 global counter (8 arrivals) -> gate. Monotonic counts.
// Cross-block data uses relaxed agent atomics (coherent path), so no fences.
__device__ __forceinline__ void gridbar2(unsigned* bar, unsigned target, int grp){
  __syncthreads();
  if (threadIdx.x == 0){
    unsigned v = __hip_atomic_fetch_add(bar + grp*32, 1u, __ATOMIC_RELAXED, __HIP_MEMORY_SCOPE_AGENT);
    if (v == target*16u - 1u){
      unsigned g2 = __hip_atomic_fetch_add(bar + 256, 1u, __ATOMIC_RELAXED, __HIP_MEMORY_SCOPE_AGENT);
      if (g2 == target*8u - 1u)
        AST(bar + 288, target);
    }
    while (ALD(bar + 288) < target) __builtin_amdgcn_s_sleep(2);
    asm volatile("" ::: "memory");
  }
  __syncthreads();
}

// ---------------- setup kernels ----------------

__global__ void k_init0(unsigned* __restrict__ bar, unsigned long long* __restrict__ mz){
  int t = threadIdx.x;
  if (t < 512) AST(bar + t, 0u);
  if (t < 128) AST(mz + t, 0ull);
}

__global__ __launch_bounds__(256) void k_transpose(const float* __restrict__ in, float* __restrict__ out, int R, int C){
  __shared__ float tile[64][65];
  int c0 = blockIdx.x*64, r0 = blockIdx.y*64;
  int tid = threadIdx.x;
  int cl = tid & 63, q = tid >> 6;
  #pragma unroll
  for (int i=0;i<16;i++){
    int r = q + i*4;
    float v = 0.0f;
    if (r0 + r < R && c0 + cl < C) v = in[(size_t)(r0+r)*C + c0 + cl];
    tile[r][cl] = v;
  }
  __syncthreads();
  #pragma unroll
  for (int i=0;i<16;i++){
    int c = q + i*4;
    if (c0 + c < C && r0 + cl < R)
      out[(size_t)(c0+c)*R + r0 + cl] = tile[cl][c];
  }
}

// f32 [R][C] -> bf16 [C][R] (hi only; used for W_v)
__global__ __launch_bounds__(256) void k_convT(const float* __restrict__ in, u16* __restrict__ hi, int R, int C){
  __shared__ float tile[64][65];
  int c0 = blockIdx.x*64, r0 = blockIdx.y*64;
  int tid = threadIdx.x;
  int cl = tid & 63, q = tid >> 6;
  #pragma unroll
  for (int i=0;i<16;i++){
    int r = q + i*4;
    float v = 0.0f;
    if (r0 + r < R && c0 + cl < C) v = in[(size_t)(r0+r)*C + c0 + cl];
    tile[r][cl] = v;
  }
  __syncthreads();
  #pragma unroll
  for (int i=0;i<16;i++){
    int c = q + i*4;
    if (c0 + c < C && r0 + cl < R)
      hi[(size_t)(c0+c)*R + r0 + cl] = f2bf(tile[cl][c]);
  }
}

// W_enc [1024][512] f32 -> WencT3 [512][3072] bf16 rows = [hi | lo | hi]
__global__ __launch_bounds__(256) void k_convT3(const float* __restrict__ in, u16* __restrict__ out){
  __shared__ float tile[64][65];
  int c0 = blockIdx.x*64, r0 = blockIdx.y*64;   // grid (8,16)
  int tid = threadIdx.x;
  int cl = tid & 63, q = tid >> 6;
  #pragma unroll
  for (int i=0;i<16;i++){
    int r = q + i*4;
    tile[r][cl] = in[(size_t)(r0+r)*A_ + c0 + cl];
  }
  __syncthreads();
  #pragma unroll
  for (int i=0;i<16;i++){
    int c = q + i*4;
    float v = tile[cl][c];
    u16 h = f2bf(v);
    u16 lo = f2bf(v - bf2f(h));
    size_t o = (size_t)(c0+c)*3072 + (r0+cl);
    out[o] = h;
    out[o + 1024] = lo;
    out[o + 2048] = h;
  }
}

// enc [12800][1024] f32 -> enc3 [12800][3072] bf16 rows = [hi | hi | lo]
__global__ void k_conv3(const float* __restrict__ in, u16* __restrict__ out, int n4){
  int i = blockIdx.x*256 + threadIdx.x;
  if (i >= n4) return;
  float4 x = reinterpret_cast<const float4*>(in)[i];
  u16 h0v=f2bf(x.x), h1v=f2bf(x.y), h2v=f2bf(x.z), h3v=f2bf(x.w);
  uint2 hv; hv.x = (unsigned)h0v | ((unsigned)h1v << 16); hv.y = (unsigned)h2v | ((unsigned)h3v << 16);
  uint2 lv;
  lv.x = (unsigned)f2bf(x.x - bf2f(h0v)) | ((unsigned)f2bf(x.y - bf2f(h1v)) << 16);
  lv.y = (unsigned)f2bf(x.z - bf2f(h2v)) | ((unsigned)f2bf(x.w - bf2f(h3v)) << 16);
  int row = i >> 8, c = (i & 255)*4;
  size_t base = (size_t)row*3072 + c;
  *reinterpret_cast<uint2*>(out + base)        = hv;
  *reinterpret_cast<uint2*>(out + base + 1024) = hv;
  *reinterpret_cast<uint2*>(out + base + 2048) = lv;
}

// G2[t][g][hidx][b] = b_ih + b_hh + emb @ W_ih^T   (layout for k_recur coalesced reads)
__global__ __launch_bounds__(256) void k_gih(const float* __restrict__ emb, const float* __restrict__ WihT,
    const float* __restrict__ b_ih, const float* __restrict__ b_hh, float* __restrict__ G){
  __shared__ float em[8][128];
  int r0 = blockIdx.x*8;
  int tid = threadIdx.x;
  #pragma unroll
  for (int i=0;i<4;i++){
    int e = i*256 + tid;
    em[e>>7][e&127] = emb[(size_t)(r0 + (e>>7))*E_ + (e&127)];
  }
  __syncthreads();
  for (int jj=0;jj<8;jj++){
    int j = jj*256 + tid;
    float bias = b_ih[j] + b_hh[j];
    float acc[8];
    #pragma unroll
    for (int r=0;r<8;r++) acc[r] = bias;
    for (int e=0;e<128;e++){
      float wv = WihT[(size_t)e*H4_ + j];
      #pragma unroll
      for (int r=0;r<8;r++) acc[r] += em[r][e]*wv;
    }
    #pragma unroll
    for (int rr=0;rr<8;rr++){
      int r = r0 + rr;
      G[(size_t)(r & 31)*65536 + (size_t)(j >> 9)*16384 + (size_t)(j & 511)*32 + (r >> 5)] = acc[rr];
    }
  }
}

// ---------------- MFMA bf16 GEMM (coalesced LDS epilogue, optional stats) ----------------
__global__ __launch_bounds__(256, 2) void k_gemm_bf16(
    const u16* __restrict__ A, int lda, const u16* __restrict__ Bt, int ldb,
    const float* __restrict__ bias, float* __restrict__ Cf, u16* __restrict__ Cbf, int ldc,
    int M, int N, int K, float2* __restrict__ stats, int nblk)
{
  __shared__ __align__(16) float CsF[128*132];
  __shared__ float rs[128], rs2[128];
  u16* As = reinterpret_cast<u16*>(CsF);
  u16* Bs = As + 128*64;
  const int tid = threadIdx.x;
  const int m0 = blockIdx.y * 128;
  const int n0 = blockIdx.x * 128;
  const int l  = tid & 63;
  const int wavebase = tid & ~63;
  const int wid = tid >> 6;
  const int wm = (wid >> 1) * 64;
  const int wn = (wid & 1) * 64;

  v4f acc[4][4];
  v4f vzero = {0.0f, 0.0f, 0.0f, 0.0f};
  #pragma unroll
  for (int i=0;i<4;i++)
    #pragma unroll
    for (int j=0;j<4;j++) acc[i][j] = vzero;

  for (int k0 = 0; k0 < K; k0 += 64){
    __syncthreads();
    #pragma unroll
    for (int jj=0;jj<4;jj++){
      int fc = jj*256 + tid;
      int row = fc >> 3;
      int cc = (fc & 7) ^ (row & 7);
      const u16* g = A + (size_t)(m0 + row)*lda + k0 + cc*8;
      __builtin_amdgcn_global_load_lds(
        (__attribute__((address_space(1))) void*)g,
        (__attribute__((address_space(3))) void*)(As + (size_t)(jj*256 + wavebase)*8),
        16, 0, 0);
    }
    #pragma unroll
    for (int jj=0;jj<4;jj++){
      int fc = jj*256 + tid;
      int row = fc >> 3;
      int cc = (fc & 7) ^ (row & 7);
      int rn = n0 + row; if (rn > N-1) rn = N-1;
      const u16* g = Bt + (size_t)rn*ldb + k0 + cc*8;
      __builtin_amdgcn_global_load_lds(
        (__attribute__((address_space(1))) void*)g,
        (__attribute__((address_space(3))) void*)(Bs + (size_t)(jj*256 + wavebase)*8),
        16, 0, 0);
    }
    __syncthreads();
    #pragma unroll
    for (int ks=0;ks<2;ks++){
      v8s af[4], bfr[4];
      #pragma unroll
      for (int rt=0;rt<4;rt++){
        int r = wm + rt*16 + (l & 15);
        int cs = (ks*4 + (l >> 4)) ^ (r & 7);
        af[rt] = *reinterpret_cast<const v8s*>(As + r*64 + cs*8);
      }
      #pragma unroll
      for (int nt=0;nt<4;nt++){
        int r = wn + nt*16 + (l & 15);
        int cs = (ks*4 + (l >> 4)) ^ (r & 7);
        bfr[nt] = *reinterpret_cast<const v8s*>(Bs + r*64 + cs*8);
      }
      #pragma unroll
      for (int rt=0;rt<4;rt++)
        #pragma unroll
        for (int nt=0;nt<4;nt++)
          acc[rt][nt] = __builtin_amdgcn_mfma_f32_16x16x32_bf16(af[rt], bfr[nt], acc[rt][nt], 0, 0, 0);
    }
  }

  const int cl = l & 15;
  const int rg = (l >> 4) * 4;
  float cvv[4][4][4];
  #pragma unroll
  for (int rt=0;rt<4;rt++)
    #pragma unroll
    for (int nt=0;nt<4;nt++){
      int gc = n0 + wn + nt*16 + cl;
      float bv = (bias && gc < N) ? bias[gc] : 0.0f;
      #pragma unroll
      for (int i=0;i<4;i++) cvv[rt][nt][i] = acc[rt][nt][i] + bv;
    }

  if (stats){
    float tsm[4][4];
    #pragma unroll
    for (int rt=0;rt<4;rt++)
      #pragma unroll
      for (int i=0;i<4;i++){
        float mx = -1e30f;
        #pragma unroll
        for (int nt=0;nt<4;nt++){
          int gc = n0 + wn + nt*16 + cl;
          if (gc < N) mx = fmaxf(mx, cvv[rt][nt][i]);
        }
        #pragma unroll
        for (int off=1; off<16; off<<=1) mx = fmaxf(mx, __shfl_xor(mx, off, 64));
        if (wn == 0 && cl == 0) rs[wm + rt*16 + rg + i] = mx;
        tsm[rt][i] = mx;
      }
    __syncthreads();
    if (wn != 0){
      #pragma unroll
      for (int rt=0;rt<4;rt++)
        #pragma unroll
        for (int i=0;i<4;i++){
          float c = fmaxf(tsm[rt][i], rs[wm + rt*16 + rg + i]);
          if (cl == 0) rs[wm + rt*16 + rg + i] = c;
        }
    }
    __syncthreads();
    #pragma unroll
    for (int rt=0;rt<4;rt++)
      #pragma unroll
      for (int i=0;i<4;i++){
        float rm = rs[wm + rt*16 + rg + i];
        float sm = 0.0f;
        #pragma unroll
        for (int nt=0;nt<4;nt++){
          int gc = n0 + wn + nt*16 + cl;
          if (gc < N) sm += __expf(cvv[rt][nt][i] - rm);
        }
        #pragma unroll
        for (int off=1; off<16; off<<=1) sm += __shfl_xor(sm, off, 64);
        tsm[rt][i] = sm;
        if (wn == 0 && cl == 0) rs2[wm + rt*16 + rg + i] = sm;
      }
    __syncthreads();
    if (wn != 0 && cl == 0){
      #pragma unroll
      for (int rt=0;rt<4;rt++)
        #pragma unroll
        for (int i=0;i<4;i++){
          int row = wm + rt*16 + rg + i;
          stats[(size_t)(m0 + row)*nblk + blockIdx.x] =
            make_float2(rs[row], tsm[rt][i] + rs2[row]);
        }
    }
  }

  __syncthreads();
  #pragma unroll
  for (int rt=0;rt<4;rt++)
    #pragma unroll
    for (int nt=0;nt<4;nt++)
      #pragma unroll
      for (int i=0;i<4;i++)
        CsF[(wm + rt*16 + rg + i)*132 + wn + nt*16 + cl] = cvv[rt][nt][i];
  __syncthreads();
  #pragma unroll
  for (int it=0; it<16; ++it){
    int row = (tid >> 5) + it*8;
    int c4 = tid & 31;
    int gc = n0 + c4*4;
    int gr = m0 + row;
    if (gc < N){
      float4 v = *reinterpret_cast<const float4*>(&CsF[row*132 + c4*4]);
      if (Cf) *reinterpret_cast<float4*>(Cf + (size_t)gr*ldc + gc) = v;
      if (Cbf){
        uint2 o;
        o.x = (unsigned)f2bf(v.x) | ((unsigned)f2bf(v.y) << 16);
        o.y = (unsigned)f2bf(v.z) | ((unsigned)f2bf(v.w) << 16);
        *reinterpret_cast<uint2*>(Cbf + (size_t)gr*ldc + gc) = o;
      }
    }
  }
}

// fallback f32 GEMM for W_v when ws too small
__global__ __launch_bounds__(256) void k_wv_f32(
  const float* __restrict__ Aah, const float* __restrict__ Wv, const float* __restrict__ bv,
  float* __restrict__ Cl)
{
  __shared__ float Asf[32][68];
  __shared__ float Bsf[32][64];
  int n0 = blockIdx.x*64, m0 = blockIdx.y*64;
  int tid = threadIdx.x;
  int tx = tid & 15, ty = tid >> 4;
  float acc[4][4] = {};
  for (int kc = 0; kc < H_; kc += 32){
    __syncthreads();
    #pragma unroll
    for (int i=0;i<8;i++){
      int e = i*256 + tid;
      Asf[e & 31][e >> 5] = Aah[(size_t)(m0 + (e >> 5))*H_ + kc + (e & 31)];
    }
    #pragma unroll
    for (int i=0;i<8;i++){
      int e = i*256 + tid;
      int nc = n0 + (e & 63); if (nc >= V_) nc = V_-1;
      Bsf[e >> 6][e & 63] = Wv[(size_t)(kc + (e >> 6))*V_ + nc];
    }
    __syncthreads();
    #pragma unroll
    for (int k=0;k<32;k++){
      float4 a4 = *reinterpret_cast<const float4*>(&Asf[k][ty*4]);
      float4 b4 = *reinterpret_cast<const float4*>(&Bsf[k][tx*4]);
      float av[4] = {a4.x, a4.y, a4.z, a4.w};
      float bv4[4] = {b4.x, b4.y, b4.z, b4.w};
      #pragma unroll
      for (int i=0;i<4;i++)
        #pragma unroll
        for (int j=0;j<4;j++)
          acc[i][j] = __builtin_fmaf(av[i], bv4[j], acc[i][j]);
    }
  }
  #pragma unroll
  for (int i=0;i<4;i++){
    int rr = m0 + ty*4 + i;
    #pragma unroll
    for (int j=0;j<4;j++){
      int cc = n0 + tx*4 + j;
      if (cc < V_) Cl[(size_t)rr*V_ + cc] = acc[i][j] + bv[cc];
    }
  }
}

// ---------------- persistent fused recurrence ----------------
// iter i: X = [stage h_i; dec_{i-1} slice; gates_i; publish h_{i+1}, dec(par)]
//   -> 1 hierarchical grid barrier ->
// Y = [read dec(par); 100 scores for (bb,sq); local (m,Z); 4-way tag-spin
//      exchange via packed u64 (gen tag in Z low mantissa bits); softmax;
//      attn/cov for own 100].  33 barriers total, no redundant score work.
__global__ __launch_bounds__(512, 1) void k_recur(
  const float* __restrict__ W_hh, const float* __restrict__ G2,
  const float* __restrict__ W_decT, const u16* __restrict__ ep_bf,
  const float* __restrict__ w_cov, const float* __restrict__ v_att,
  const void* __restrict__ maskp, const float* __restrict__ h0,
  const float* __restrict__ c0, float* __restrict__ h_gT,
  float* __restrict__ dec_g, unsigned long long* __restrict__ mz,
  float* __restrict__ catbuf, float* __restrict__ attns, float* __restrict__ covs,
  unsigned* __restrict__ bar)
{
  const int beta = blockIdx.x;
  const int tid = threadIdx.x;
  __shared__ float h_lds[512*33];      // 67.6 KB, [k][b] padded
  __shared__ float W_l[16][512];       // 32 KB: this block's 16 W_hh rows
  __shared__ float Wd_l[4][512];       // 8 KB: this block's 4 W_decT rows
  __shared__ float gv[4][4][32];
  __shared__ float pdec[4][4][32];
  __shared__ float c_l[128];
  __shared__ float dec_l[512];
  __shared__ float sc_l[100];
  __shared__ float cov_l[100];
  __shared__ float smz[4][2];

  const int b32 = tid & 31;
  const int hl  = (tid >> 5) & 3;
  const int g   = tid >> 7;           // gate id; also k-quarter for dec
  const int w = tid >> 6, l = tid & 63;
  const int grp = beta & 7;           // barrier arrival group (XCD under round-robin)
  // Y-phase mapping: 4 blocks of a batch share beta&7 (same group/XCD)
  const int bb = (beta & 7)*4 + (beta >> 5);
  const int sq = (beta >> 3) & 3;

  // one-time staging (reused across all 32 steps)
  for (int idx = tid; idx < 16*512; idx += 512){
    int row = idx >> 9;               // row = g*4 + hl
    int k = idx & 511;
    W_l[row][k] = W_hh[((size_t)(row >> 2)*H_ + beta*4 + (row & 3))*H_ + k];
  }
  for (int idx = tid; idx < 4*512; idx += 512)
    Wd_l[idx >> 9][idx & 511] = W_decT[(size_t)(beta*4 + (idx >> 9))*H_ + (idx & 511)];
  if (tid < 128) c_l[tid] = c0[(size_t)(tid & 31)*H_ + beta*4 + (tid >> 5)];
  if (tid < 100) cov_l[tid] = 0.f;

  const unsigned* m32p = (const unsigned*)maskp;
  const unsigned char* m8p = (const unsigned char*)maskp;
  const bool bytemode = (m32p[0] == 0x01010101u);

  float wc8[8], va8[8];
  {
    int a0 = l*8;
    #pragma unroll
    for (int j=0;j<8;j++){ wc8[j] = w_cov[a0+j]; va8[j] = v_att[a0+j]; }
  }

  unsigned gen = 0;
  for (int i = 0; i <= T_; ++i){
    const int par = i & 1;
    // ---- X: stage h_i into LDS (coalesced) ----
    if (i == 0){
      #pragma unroll
      for (int j=0;j<32;j++){
        int flat = j*512 + tid;              // h0 layout [b][k]
        h_lds[(flat & 511)*33 + (flat >> 9)] = h0[flat];
      }
    } else {
      const float* hp = h_gT + (size_t)par*16384;   // layout [k][b]
      #pragma unroll
      for (int j=0;j<32;j++){
        int flat = j*512 + tid;
        h_lds[(flat >> 5)*33 + (flat & 31)] = ALD(hp + flat);
      }
    }
    __syncthreads();

    // ---- dec_{i-1}: a = beta*4+hl, k-quarter g ----
    if (i > 0){
      float acc = 0.f;
      const float* Wr = &Wd_l[hl][g*128];
      const int kq = g*128;
      #pragma unroll 8
      for (int k=0;k<128;k++)
        acc = __builtin_fmaf(h_lds[(kq + k)*33 + b32], Wr[k], acc);
      pdec[g][hl][b32] = acc;
    }
    // ---- gates_i: full-K dot ----
    if (i < T_){
      const float* Wr = &W_l[g*4 + hl][0];
      float x0=0.f, x1=0.f, x2=0.f, x3=0.f;
      #pragma unroll 8
      for (int k=0;k<128;k++){
        x0 = __builtin_fmaf(h_lds[(k      )*33 + b32], Wr[k      ], x0);
        x1 = __builtin_fmaf(h_lds[(k + 128)*33 + b32], Wr[k + 128], x1);
        x2 = __builtin_fmaf(h_lds[(k + 256)*33 + b32], Wr[k + 256], x2);
        x3 = __builtin_fmaf(h_lds[(k + 384)*33 + b32], Wr[k + 384], x3);
      }
      gv[g][hl][b32] = (x0 + x1) + (x2 + x3);
    }
    __syncthreads();

    if (i > 0 && tid < 128){
      int al = tid >> 5;
      float d = pdec[0][al][b32] + pdec[1][al][b32] + pdec[2][al][b32] + pdec[3][al][b32];
      AST(dec_g + (size_t)par*B_*A_ + (size_t)b32*A_ + beta*4 + al, d);
    }
    if (i < T_ && tid < 128){
      int hh = tid >> 5;
      int hidx = beta*4 + hh;
      const float* Gr = G2 + (size_t)i*65536 + (size_t)hidx*32 + b32;
      float gi = gv[0][hh][b32] + Gr[0];
      float gf = gv[1][hh][b32] + Gr[16384];
      float gg = gv[2][hh][b32] + Gr[32768];
      float go = gv[3][hh][b32] + Gr[49152];
      float co = c_l[tid];
      float cn = fsig(gf)*co + fsig(gi)*ftanh(gg);
      float hn = fsig(go)*ftanh(cn);
      c_l[tid] = cn;
      AST(h_gT + (size_t)(par^1)*16384 + (size_t)hidx*32 + b32, hn);
      catbuf[(size_t)(b32*T_ + i)*H3_ + H2_ + hidx] = hn;
    }
    gridbar2(bar, ++gen, grp);

    // ---- Y: scores_{i-1} for s-quarter sq of batch bb ----
    if (i > 0){
      const int r = bb*T_ + (i-1);
      dec_l[tid] = ALD(dec_g + (size_t)par*B_*A_ + (size_t)bb*A_ + tid);
      __syncthreads();
      int a0 = l*8;
      float dec8[8];
      #pragma unroll
      for (int j=0;j<8;j++) dec8[j] = dec_l[a0+j];
      for (int it=0; it<13; ++it){
        int sl = w + it*8;
        if (sl < 100){
          int s = sq*100 + sl;
          float cv = cov_l[sl];
          uint4 e8 = *reinterpret_cast<const uint4*>(ep_bf + (size_t)(bb*S_ + s)*A_ + a0);
          unsigned uu[4] = {e8.x, e8.y, e8.z, e8.w};
          float part = 0.f;
          #pragma unroll
          for (int j=0;j<4;j++){
            float xa = bf2f((u16)(uu[j] & 0xFFFFu)) + dec8[2*j]   + cv*wc8[2*j];
            part += va8[2*j]*ftanh(xa);
            float xb = bf2f((u16)(uu[j] >> 16))     + dec8[2*j+1] + cv*wc8[2*j+1];
            part += va8[2*j+1]*ftanh(xb);
          }
          part = wsum(part);
          if (l == 0){
            bool on = bytemode ? (m8p[bb*S_+s] != 0) : (m32p[bb*S_+s] != 0u);
            sc_l[sl] = on ? part : -1e9f;
          }
        }
      }
      __syncthreads();
      // local (m,Z) over this block's 100 scores; publish with gen tag in Z mantissa
      if (tid < 64){
        float x1v = sc_l[l];
        float x2v = (l + 64 < 100) ? sc_l[l + 64] : -1e30f;
        float m = wmax(fmaxf(x1v, x2v));
        float z = __expf(x1v - m) + ((l + 64 < 100) ? __expf(x2v - m) : 0.f);
        z = wsum(z);
        if (l == 0){
          unsigned zt = (__float_as_uint(z) & ~255u) | (gen & 255u);
          unsigned long long pk = ((unsigned long long)zt << 32) | (unsigned long long)__float_as_uint(m);
          AST(mz + bb*4 + sq, pk);
        }
      }
      // 4-way tag-spin exchange (no global barrier)
      if (tid < 4){
        unsigned long long v;
        do {
          v = ALD(mz + bb*4 + tid);
          if (((unsigned)(v >> 32) & 255u) == (gen & 255u)) break;
          __builtin_amdgcn_s_sleep(1);
        } while (true);
        smz[tid][0] = __uint_as_float((unsigned)v);
        smz[tid][1] = __uint_as_float((unsigned)(v >> 32));
      }
      __syncthreads();
      float gm = fmaxf(fmaxf(smz[0][0], smz[1][0]), fmaxf(smz[2][0], smz[3][0]));
      float gZ = smz[0][1]*__expf(smz[0][0]-gm) + smz[1][1]*__expf(smz[1][0]-gm)
               + smz[2][1]*__expf(smz[2][0]-gm) + smz[3][1]*__expf(smz[3][0]-gm);
      float invZ = 1.f/gZ;
      if (tid < 100){
        float av = __expf(sc_l[tid] - gm)*invZ;
        int s = sq*100 + tid;
        float cn = cov_l[tid] + av;
        cov_l[tid] = cn;
        attns[(size_t)r*S_ + s] = av;
        covs[(size_t)r*S_ + s]  = cn;
      }
      __syncthreads();
    }
  }
}

// ---------------- post-loop kernels ----------------

// context (deferred): catbuf[:, :1024] = attns @ enc   (fp32, single enc pass)
__global__ __launch_bounds__(256, 2) void k_ctx(
  const float* __restrict__ attns, const float* __restrict__ enc, float* __restrict__ catbuf)
{
  __shared__ float att_s[32][400];
  int d0 = blockIdx.x*64, b = blockIdx.y;
  int tid = threadIdx.x;
  for (int tt=0; tt<32; ++tt)
    for (int s = tid; s < S_; s += 256)
      att_s[tt][s] = attns[(size_t)(b*T_ + tt)*S_ + s];
  __syncthreads();
  int d = d0 + (tid & 63);
  int t0 = (tid >> 6)*8;
  float acc[8] = {0,0,0,0,0,0,0,0};
  const float* encb = enc + (size_t)b*S_*H2_ + d;
  #pragma unroll 4
  for (int s=0; s<S_; ++s){
    float ev = encb[(size_t)s*H2_];
    #pragma unroll
    for (int i=0;i<8;i++) acc[i] = __builtin_fmaf(att_s[t0+i][s], ev, acc[i]);
  }
  #pragma unroll
  for (int i=0;i<8;i++)
    catbuf[(size_t)(b*T_ + t0 + i)*H3_ + d] = acc[i];
}

// fp32 tiled GEMM: dec_states = tanh(catbuf @ W_ah + b_ah); optional bf16 copy
__global__ __launch_bounds__(256) void k_ahgemm(
  const float* __restrict__ Acat, const float* __restrict__ W_ah, const float* __restrict__ b_ah,
  float* __restrict__ dec_states, u16* __restrict__ ah_bf)
{
  __shared__ float Asf[32][68];
  __shared__ float Bsf[32][64];
  int n0 = blockIdx.x*64, m0 = blockIdx.y*64;
  int tid = threadIdx.x;
  int tx = tid & 15, ty = tid >> 4;
  float acc[4][4] = {};
  for (int kc = 0; kc < H3_; kc += 32){
    __syncthreads();
    #pragma unroll
    for (int i=0;i<8;i++){
      int e = i*256 + tid;
      Asf[e & 31][e >> 5] = Acat[(size_t)(m0 + (e >> 5))*H3_ + kc + (e & 31)];
    }
    #pragma unroll
    for (int i=0;i<8;i++){
      int e = i*256 + tid;
      Bsf[e >> 6][e & 63] = W_ah[(size_t)(kc + (e >> 6))*H_ + n0 + (e & 63)];
    }
    __syncthreads();
    #pragma unroll
    for (int k=0;k<32;k++){
      float4 a4 = *reinterpret_cast<const float4*>(&Asf[k][ty*4]);
      float4 b4 = *reinterpret_cast<const float4*>(&Bsf[k][tx*4]);
      float av[4] = {a4.x, a4.y, a4.z, a4.w};
      float bv[4] = {b4.x, b4.y, b4.z, b4.w};
      #pragma unroll
      for (int i=0;i<4;i++)
        #pragma unroll
        for (int j=0;j<4;j++)
          acc[i][j] = __builtin_fmaf(av[i], bv[j], acc[i][j]);
    }
  }
  #pragma unroll
  for (int i=0;i<4;i++){
    int rr = m0 + ty*4 + i;
    #pragma unroll
    for (int j=0;j<4;j++){
      int cc = n0 + tx*4 + j;
      float v = ftanh(acc[i][j] + b_ah[cc]);
      dec_states[(size_t)rr*H_ + cc] = v;
      if (ah_bf) ah_bf[(size_t)rr*H_ + cc] = f2bf(v);
    }
  }
}

__global__ __launch_bounds__(512) void k_pgen(const float* __restrict__ catbuf, const float* __restrict__ emb,
  const float* __restrict__ W_pg, const float* __restrict__ b_pg, float* __restrict__ pgens)
{
  int w = threadIdx.x >> 6, l = threadIdx.x & 63;
  int r = blockIdx.x*8 + w;
  float part = 0.0f;
  for (int d = l; d < PGK_; d += 64){
    float x = (d < H3_) ? catbuf[(size_t)r*H3_ + d] : emb[(size_t)r*E_ + (d - H3_)];
    part += x*W_pg[d];
  }
  part = wsum(part);
  if (l == 0) pgens[r] = fsig(part + b_pg[0]);
}

// per-row final: stats merge -> bitmask+hash scatter -> fast log transform
__global__ __launch_bounds__(512) void k_final2(
  float* __restrict__ logits, const float* __restrict__ pgens,
  const float* __restrict__ attns, const int* __restrict__ src,
  const float2* __restrict__ stats, int nblk)
{
  __shared__ unsigned bits[1568];
  __shared__ unsigned keys[1024];
  __shared__ float vals[1024];
  __shared__ float sred[18];
  int r = blockIdx.x;
  int b = r >> 5;
  int tid = threadIdx.x;
  int w = tid >> 6, l = tid & 63;
  float* row = logits + (size_t)r*V_;

  for (int i = tid; i < 1568; i += 512) bits[i] = 0u;
  for (int i = tid; i < 1024; i += 512){ keys[i] = 0xFFFFFFFFu; vals[i] = 0.0f; }

  if (stats){
    float m = -1e30f, Z = 0.0f;
    if (tid < nblk){ float2 st = stats[(size_t)r*nblk + tid]; m = st.x; Z = st.y; }
    #pragma unroll
    for (int off=32; off>0; off>>=1){
      float mo = __shfl_xor(m, off, 64);
      float Zo = __shfl_xor(Z, off, 64);
      float nm = fmaxf(m, mo);
      Z = Z*__expf(m - nm) + Zo*__expf(mo - nm);
      m = nm;
    }
    if (l == 0){ sred[w*2] = m; sred[w*2+1] = Z; }
    __syncthreads();
    if (tid == 0){
      float gm = -1e30f, gz = 0.0f;
      #pragma unroll
      for (int i=0;i<8;i++){
        float mi = sred[i*2], zi = sred[i*2+1];
        float nm = fmaxf(gm, mi);
        gz = gz*__expf(gm - nm) + zi*__expf(mi - nm);
        gm = nm;
      }
      sred[16] = gm; sred[17] = gz;
    }
    __syncthreads();
  } else {
    float m = -1e30f;
    for (int j = tid; j < V_/4; j += 512){
      float4 x = reinterpret_cast<const float4*>(row)[j];
      m = fmaxf(fmaxf(m, x.x), fmaxf(fmaxf(x.y, x.z), x.w));
    }
    m = wmax(m);
    if (l == 0) sred[w] = m;
    __syncthreads();
    if (tid == 0){
      float gm = -1e30f;
      #pragma unroll
      for (int i=0;i<8;i++) gm = fmaxf(gm, sred[i]);
      sred[16] = gm;
    }
    __syncthreads();
    float gm = sred[16];
    float z = 0.0f;
    for (int j = tid; j < V_/4; j += 512){
      float4 x = reinterpret_cast<const float4*>(row)[j];
      z += __expf(x.x-gm) + __expf(x.y-gm) + __expf(x.z-gm) + __expf(x.w-gm);
    }
    z = wsum(z);
    if (l == 0) sred[8 + w] = z;
    __syncthreads();
    if (tid == 0){
      float gz = 0.0f;
      #pragma unroll
      for (int i=0;i<8;i++) gz += sred[8 + i];
      sred[17] = gz;
    }
    __syncthreads();
  }

  float gm = sred[16];
  float gZ = sred[17];
  float pg = pgens[r];
  float scale = pg / gZ;
  float lscale = __logf(scale);

  if (tid < S_){
    int tok = src[b*S_ + tid];
    float add = (1.0f - pg)*attns[(size_t)r*S_ + tid];
    atomicOr(&bits[tok >> 5], 1u << (tok & 31));
    unsigned h = ((unsigned)tok * 2654435761u) >> 22;
    while (true){
      unsigned prev = atomicCAS(&keys[h], 0xFFFFFFFFu, (unsigned)tok);
      if (prev == 0xFFFFFFFFu || prev == (unsigned)tok){
        atomicAdd(&vals[h], add);
        break;
      }
      h = (h + 1) & 1023;
    }
  }
  __syncthreads();

  for (int j = tid; j < V_/4; j += 512){
    float4 x = reinterpret_cast<const float4*>(row)[j];
    int v = 4*j;
    float o[4];
    float xv[4] = {x.x, x.y, x.z, x.w};
    #pragma unroll
    for (int k=0;k<4;k++){
      int vv = v + k;
      bool hit = (bits[vv >> 5] >> (vv & 31)) & 1u;
      float tt = xv[k] - gm + lscale;
      if (!hit && tt > -25.0f){
        o[k] = tt;
      } else {
        float pval = __expf(xv[k] - gm)*scale;
        if (hit){
          unsigned h = ((unsigned)vv * 2654435761u) >> 22;
          while (keys[h] != 0xFFFFFFFFu){
            if (keys[h] == (unsigned)vv){ pval += vals[h]; break; }
            h = (h + 1) & 1023;
          }
        }
        o[k] = __logf(pval + 1e-20f);
      }
    }
    reinterpret_cast<float4*>(row)[j] = make_float4(o[0], o[1], o[2], o[3]);
  }
}

// ---------------- host ----------------

extern "C" void kernel_launch(void* const* d_in, const int* in_sizes, int n_in,
                              void* d_out, int out_size, void* d_ws, size_t ws_size,
                              hipStream_t stream)
{
  const int* src_tokens = (const int*)d_in[0];
  const float* embedded = (const float*)d_in[1];
  const float* enc      = (const float*)d_in[2];
  const void*  maskp    = (const void*)d_in[3];
  const float* h0  = (const float*)d_in[4];
  const float* c0  = (const float*)d_in[5];
  const float* W_ih = (const float*)d_in[6];
  const float* W_hh = (const float*)d_in[7];
  const float* b_ih = (const float*)d_in[8];
  const float* b_hh = (const float*)d_in[9];
  const float* W_enc = (const float*)d_in[10];
  const float* W_dec = (const float*)d_in[11];
  const float* w_cov = (const float*)d_in[12];
  const float* b_att = (const float*)d_in[13];
  const float* v_att = (const float*)d_in[14];
  const float* W_ah  = (const float*)d_in[15];
  const float* b_ah  = (const float*)d_in[16];
  const float* W_pg  = (const float*)d_in[17];
  const float* b_pg  = (const float*)d_in[18];
  const float* W_v   = (const float*)d_in[19];
  const float* b_v   = (const float*)d_in[20];
  (void)in_sizes; (void)n_in; (void)out_size;

  float* outp = (float*)d_out;
  float* logps = outp;                                  // (B,T,V)   204.8 MB
  float* dec_states = logps + (size_t)R_*V_;            // (B,T,H)
  float* attns = dec_states + (size_t)R_*H_;            // (B,T,S)
  float* covs  = attns + (size_t)R_*S_;                 // (B,T,S)
  float* pgens = covs + (size_t)R_*S_;                  // (B,T)

  // big transients live INSIDE the logps output region (dead until W_v GEMM)
  char* sp = (char*)logps;
  auto salloc = [&](size_t bytes) -> void* {
    void* p = (void*)sp;
    sp += (bytes + 255) & ~(size_t)255;
    return p;
  };
  unsigned* bar = (unsigned*)salloc(2048);
  unsigned long long* mz = (unsigned long long*)salloc((size_t)B_*4*8);
  u16* ep_bf    = (u16*)salloc((size_t)B_*S_*A_*2);        // 13.1 MB
  u16* enc3     = (u16*)salloc((size_t)B_*S_*3072*2);      // 78.6 MB
  u16* WencT3   = (u16*)salloc((size_t)A_*3072*2);         // 3.1 MB
  float* WihT   = (float*)salloc((size_t)E_*H4_*4);        // 1 MB
  float* W_decT = (float*)salloc((size_t)H_*A_*4);         // 1 MB
  float* G2     = (float*)salloc((size_t)R_*H4_*4);        // 8.4 MB [t][g][hidx][b]
  float* catbuf = (float*)salloc((size_t)R_*H3_*4);        // 6.3 MB [context | h]
  float* dec_g  = (float*)salloc((size_t)2*B_*A_*4);       // 128 KB double-buffered
  float* h_gT   = (float*)salloc((size_t)2*H_*B_*4);       // 128 KB double-buffered [k][b]
  // total ~112 MB < 204.8 MB -- all consumed before W_v GEMM writes logps

  // d_ws: only buffers live WHILE logps is being written
  char* wp = (char*)d_ws;
  auto walloc = [&](size_t bytes) -> void* {
    void* p = (void*)wp;
    wp += (bytes + 255) & ~(size_t)255;
    return p;
  };
  u16* ah_bf = (u16*)walloc((size_t)R_*H_*2);              // 1.05 MB
  u16* WvT   = (u16*)walloc((size_t)V_*H_*2);              // 51.2 MB
  float2* stats = (float2*)walloc((size_t)R_*NBLKV_*8);    // 3.2 MB
  const size_t ws_fast  = (size_t)R_*H_*2 + (size_t)V_*H_*2 + 512;
  const size_t ws_stats = ws_fast + (size_t)R_*NBLKV_*8 + 256;
  const bool fast_wv   = (ws_size >= ws_fast);
  const bool use_stats = (ws_size >= ws_stats);

  // setup
  k_init0<<<1, 512, 0, stream>>>(bar, mz);
  k_transpose<<<dim3(2,32), 256, 0, stream>>>(W_ih, WihT, H4_, E_);
  k_transpose<<<dim3(8,8), 256, 0, stream>>>(W_dec, W_decT, H_, A_);
  k_gih<<<128, 256, 0, stream>>>(embedded, WihT, b_ih, b_hh, G2);
  k_conv3<<<(B_*S_*H2_/4 + 255)/256, 256, 0, stream>>>(enc, enc3, B_*S_*H2_/4);
  k_convT3<<<dim3(8,16), 256, 0, stream>>>(W_enc, WencT3);
  if (fast_wv)
    k_convT<<<dim3((V_+63)/64, 8), 256, 0, stream>>>(W_v, WvT, H_, V_);

  // enc_proj: single split-bf16 GEMM (K=3072), bf16 output + b_att
  k_gemm_bf16<<<dim3(A_/128, (B_*S_)/128), 256, 0, stream>>>(
      enc3, 3072, WencT3, 3072, b_att, nullptr, ep_bf, A_, B_*S_, A_, 3072, nullptr, 0);

  // fused persistent recurrence (one hierarchical barrier per step)
  k_recur<<<GRB_, 512, 0, stream>>>(W_hh, G2, W_decT, ep_bf, w_cov, v_att, maskp,
                                    h0, c0, h_gT, dec_g, mz,
                                    catbuf, attns, covs, bar);

  // deferred contexts + batched tail
  k_ctx<<<dim3(16, 32), 256, 0, stream>>>(attns, enc, catbuf);
  k_ahgemm<<<dim3(8,16), 256, 0, stream>>>(catbuf, W_ah, b_ah, dec_states, fast_wv ? ah_bf : (u16*)nullptr);
  k_pgen<<<128, 512, 0, stream>>>(catbuf, embedded, W_pg, b_pg, pgens);

  // logits
  if (fast_wv)
    k_gemm_bf16<<<dim3(NBLKV_, R_/128), 256, 0, stream>>>(
        ah_bf, H_, WvT, H_, b_v, logps, nullptr, V_, R_, V_, H_,
        use_stats ? stats : nullptr, NBLKV_);
  else
    k_wv_f32<<<dim3((V_+63)/64, R_/64), 256, 0, stream>>>(dec_states, W_v, b_v, logps);

  k_final2<<<R_, 512, 0, stream>>>(logps, pgens, attns, src_tokens,
                                   (fast_wv && use_stats) ? stats : nullptr, NBLKV_);
}

// Round 8
// 1410.543 us; speedup vs baseline: 1.8551x; 1.2234x over previous
//
#include <hip/hip_runtime.h>
#include <hip/hip_bf16.h>
#include <stdint.h>
#include <stddef.h>

#define B_  32
#define S_  400
#define T_  32
#define H_  512
#define E_  128
#define V_  50000
#define A_  512
#define H2_ 1024
#define H3_ 1536
#define H4_ 2048
#define R_  1024     // B*T
#define PGK_ 1664    // 3H+E
#define NBLKV_ 391   // ceil(V/128)
#define GRB_ 128     // persistent-recurrence grid

typedef unsigned short u16;
typedef short v8s __attribute__((ext_vector_type(8)));
typedef float v4f __attribute__((ext_vector_type(4)));

__device__ __forceinline__ float fsig(float x){ return 1.0f/(1.0f + __expf(-x)); }
__device__ __forceinline__ float ftanh(float x){ float e = __expf(2.0f*x); return 1.0f - 2.0f/(e + 1.0f); }
__device__ __forceinline__ u16 f2bf(float x){ __hip_bfloat16 b = __float2bfloat16(x); return *reinterpret_cast<u16*>(&b); }
__device__ __forceinline__ float bf2f(u16 u){ __hip_bfloat16 b = *reinterpret_cast<__hip_bfloat16*>(&u); return __bfloat162float(b); }

__device__ __forceinline__ float wsum(float v){
  #pragma unroll
  for (int off = 32; off > 0; off >>= 1) v += __shfl_xor(v, off, 64);
  return v;
}
__device__ __forceinline__ float wmax(float v){
  #pragma unroll
  for (int off = 32; off > 0; off >>= 1) v = fmaxf(v, __shfl_xor(v, off, 64));
  return v;
}

#define ALD(p)    __hip_atomic_load((p), __ATOMIC_RELAXED, __HIP_MEMORY_SCOPE_AGENT)
#define AST(p,v)  __hip_atomic_store((p), (v), __ATOMIC_RELAXED, __HIP_MEMORY_SCOPE_AGENT)

// hierarchical fence-free grid barrier: 8 spread counters (16 arrivals each,
// keyed by beta&7) -> 1 global counter (8 arrivals) -> gate. Monotonic counts.
__device__ __forceinline__ void gridbar2(unsigned* bar, unsigned target, int grp){
  __syncthreads();
  if (threadIdx.x == 0){
    unsigned v = __hip_atomic_fetch_add(bar + grp*32, 1u, __ATOMIC_RELAXED, __HIP_MEMORY_SCOPE_AGENT);
    if (v == target*16u - 1u){
      unsigned g2 = __hip_atomic_fetch_add(bar + 256, 1u, __ATOMIC_RELAXED, __HIP_MEMORY_SCOPE_AGENT);
      if (g2 == target*8u - 1u)
        AST(bar + 288, target);
    }
    while (ALD(bar + 288) < target) __builtin_amdgcn_s_sleep(2);
    asm volatile("" ::: "memory");
  }
  __syncthreads();
}

// ---------------- setup kernels ----------------

__global__ void k_init0(unsigned* __restrict__ bar, unsigned long long* __restrict__ mz){
  int t = threadIdx.x;
  if (t < 512) AST(bar + t, 0u);
  if (t < 128) AST(mz + t, 0ull);
}

__global__ __launch_bounds__(256) void k_transpose(const float* __restrict__ in, float* __restrict__ out, int R, int C){
  __shared__ float tile[64][65];
  int c0 = blockIdx.x*64, r0 = blockIdx.y*64;
  int tid = threadIdx.x;
  int cl = tid & 63, q = tid >> 6;
  #pragma unroll
  for (int i=0;i<16;i++){
    int r = q + i*4;
    float v = 0.0f;
    if (r0 + r < R && c0 + cl < C) v = in[(size_t)(r0+r)*C + c0 + cl];
    tile[r][cl] = v;
  }
  __syncthreads();
  #pragma unroll
  for (int i=0;i<16;i++){
    int c = q + i*4;
    if (c0 + c < C && r0 + cl < R)
      out[(size_t)(c0+c)*R + r0 + cl] = tile[cl][c];
  }
}

// f32 [R][C] -> bf16 [C][R] (hi only; used for W_v)
__global__ __launch_bounds__(256) void k_convT(const float* __restrict__ in, u16* __restrict__ hi, int R, int C){
  __shared__ float tile[64][65];
  int c0 = blockIdx.x*64, r0 = blockIdx.y*64;
  int tid = threadIdx.x;
  int cl = tid & 63, q = tid >> 6;
  #pragma unroll
  for (int i=0;i<16;i++){
    int r = q + i*4;
    float v = 0.0f;
    if (r0 + r < R && c0 + cl < C) v = in[(size_t)(r0+r)*C + c0 + cl];
    tile[r][cl] = v;
  }
  __syncthreads();
  #pragma unroll
  for (int i=0;i<16;i++){
    int c = q + i*4;
    if (c0 + c < C && r0 + cl < R)
      hi[(size_t)(c0+c)*R + r0 + cl] = f2bf(tile[cl][c]);
  }
}

// W_enc [1024][512] f32 -> WencT3 [512][3072] bf16 rows = [hi | lo | hi]
__global__ __launch_bounds__(256) void k_convT3(const float* __restrict__ in, u16* __restrict__ out){
  __shared__ float tile[64][65];
  int c0 = blockIdx.x*64, r0 = blockIdx.y*64;   // grid (8,16)
  int tid = threadIdx.x;
  int cl = tid & 63, q = tid >> 6;
  #pragma unroll
  for (int i=0;i<16;i++){
    int r = q + i*4;
    tile[r][cl] = in[(size_t)(r0+r)*A_ + c0 + cl];
  }
  __syncthreads();
  #pragma unroll
  for (int i=0;i<16;i++){
    int c = q + i*4;
    float v = tile[cl][c];
    u16 h = f2bf(v);
    u16 lo = f2bf(v - bf2f(h));
    size_t o = (size_t)(c0+c)*3072 + (r0+cl);
    out[o] = h;
    out[o + 1024] = lo;
    out[o + 2048] = h;
  }
}

// enc [12800][1024] f32 -> enc3 [12800][3072] bf16 rows = [hi | hi | lo]
__global__ void k_conv3(const float* __restrict__ in, u16* __restrict__ out, int n4){
  int i = blockIdx.x*256 + threadIdx.x;
  if (i >= n4) return;
  float4 x = reinterpret_cast<const float4*>(in)[i];
  u16 h0v=f2bf(x.x), h1v=f2bf(x.y), h2v=f2bf(x.z), h3v=f2bf(x.w);
  uint2 hv; hv.x = (unsigned)h0v | ((unsigned)h1v << 16); hv.y = (unsigned)h2v | ((unsigned)h3v << 16);
  uint2 lv;
  lv.x = (unsigned)f2bf(x.x - bf2f(h0v)) | ((unsigned)f2bf(x.y - bf2f(h1v)) << 16);
  lv.y = (unsigned)f2bf(x.z - bf2f(h2v)) | ((unsigned)f2bf(x.w - bf2f(h3v)) << 16);
  int row = i >> 8, c = (i & 255)*4;
  size_t base = (size_t)row*3072 + c;
  *reinterpret_cast<uint2*>(out + base)        = hv;
  *reinterpret_cast<uint2*>(out + base + 1024) = hv;
  *reinterpret_cast<uint2*>(out + base + 2048) = lv;
}

// G2[t][g][hidx][b] = b_ih + b_hh + emb @ W_ih^T   (layout for k_recur coalesced reads)
__global__ __launch_bounds__(256) void k_gih(const float* __restrict__ emb, const float* __restrict__ WihT,
    const float* __restrict__ b_ih, const float* __restrict__ b_hh, float* __restrict__ G){
  __shared__ float em[8][128];
  int r0 = blockIdx.x*8;
  int tid = threadIdx.x;
  #pragma unroll
  for (int i=0;i<4;i++){
    int e = i*256 + tid;
    em[e>>7][e&127] = emb[(size_t)(r0 + (e>>7))*E_ + (e&127)];
  }
  __syncthreads();
  for (int jj=0;jj<8;jj++){
    int j = jj*256 + tid;
    float bias = b_ih[j] + b_hh[j];
    float acc[8];
    #pragma unroll
    for (int r=0;r<8;r++) acc[r] = bias;
    for (int e=0;e<128;e++){
      float wv = WihT[(size_t)e*H4_ + j];
      #pragma unroll
      for (int r=0;r<8;r++) acc[r] += em[r][e]*wv;
    }
    #pragma unroll
    for (int rr=0;rr<8;rr++){
      int r = r0 + rr;
      G[(size_t)(r & 31)*65536 + (size_t)(j >> 9)*16384 + (size_t)(j & 511)*32 + (r >> 5)] = acc[rr];
    }
  }
}

// ---------------- MFMA bf16 GEMM (coalesced LDS epilogue, optional stats) ----------------
__global__ __launch_bounds__(256, 2) void k_gemm_bf16(
    const u16* __restrict__ A, int lda, const u16* __restrict__ Bt, int ldb,
    const float* __restrict__ bias, float* __restrict__ Cf, u16* __restrict__ Cbf, int ldc,
    int M, int N, int K, float2* __restrict__ stats, int nblk)
{
  __shared__ __align__(16) float CsF[128*132];
  __shared__ float rs[128], rs2[128];
  u16* As = reinterpret_cast<u16*>(CsF);
  u16* Bs = As + 128*64;
  const int tid = threadIdx.x;
  const int m0 = blockIdx.y * 128;
  const int n0 = blockIdx.x * 128;
  const int l  = tid & 63;
  const int wavebase = tid & ~63;
  const int wid = tid >> 6;
  const int wm = (wid >> 1) * 64;
  const int wn = (wid & 1) * 64;

  v4f acc[4][4];
  v4f vzero = {0.0f, 0.0f, 0.0f, 0.0f};
  #pragma unroll
  for (int i=0;i<4;i++)
    #pragma unroll
    for (int j=0;j<4;j++) acc[i][j] = vzero;

  for (int k0 = 0; k0 < K; k0 += 64){
    __syncthreads();
    #pragma unroll
    for (int jj=0;jj<4;jj++){
      int fc = jj*256 + tid;
      int row = fc >> 3;
      int cc = (fc & 7) ^ (row & 7);
      const u16* g = A + (size_t)(m0 + row)*lda + k0 + cc*8;
      __builtin_amdgcn_global_load_lds(
        (__attribute__((address_space(1))) void*)g,
        (__attribute__((address_space(3))) void*)(As + (size_t)(jj*256 + wavebase)*8),
        16, 0, 0);
    }
    #pragma unroll
    for (int jj=0;jj<4;jj++){
      int fc = jj*256 + tid;
      int row = fc >> 3;
      int cc = (fc & 7) ^ (row & 7);
      int rn = n0 + row; if (rn > N-1) rn = N-1;
      const u16* g = Bt + (size_t)rn*ldb + k0 + cc*8;
      __builtin_amdgcn_global_load_lds(
        (__attribute__((address_space(1))) void*)g,
        (__attribute__((address_space(3))) void*)(Bs + (size_t)(jj*256 + wavebase)*8),
        16, 0, 0);
    }
    __syncthreads();
    #pragma unroll
    for (int ks=0;ks<2;ks++){
      v8s af[4], bfr[4];
      #pragma unroll
      for (int rt=0;rt<4;rt++){
        int r = wm + rt*16 + (l & 15);
        int cs = (ks*4 + (l >> 4)) ^ (r & 7);
        af[rt] = *reinterpret_cast<const v8s*>(As + r*64 + cs*8);
      }
      #pragma unroll
      for (int nt=0;nt<4;nt++){
        int r = wn + nt*16 + (l & 15);
        int cs = (ks*4 + (l >> 4)) ^ (r & 7);
        bfr[nt] = *reinterpret_cast<const v8s*>(Bs + r*64 + cs*8);
      }
      #pragma unroll
      for (int rt=0;rt<4;rt++)
        #pragma unroll
        for (int nt=0;nt<4;nt++)
          acc[rt][nt] = __builtin_amdgcn_mfma_f32_16x16x32_bf16(af[rt], bfr[nt], acc[rt][nt], 0, 0, 0);
    }
  }

  const int cl = l & 15;
  const int rg = (l >> 4) * 4;
  float cvv[4][4][4];
  #pragma unroll
  for (int rt=0;rt<4;rt++)
    #pragma unroll
    for (int nt=0;nt<4;nt++){
      int gc = n0 + wn + nt*16 + cl;
      float bv = (bias && gc < N) ? bias[gc] : 0.0f;
      #pragma unroll
      for (int i=0;i<4;i++) cvv[rt][nt][i] = acc[rt][nt][i] + bv;
    }

  if (stats){
    float tsm[4][4];
    #pragma unroll
    for (int rt=0;rt<4;rt++)
      #pragma unroll
      for (int i=0;i<4;i++){
        float mx = -1e30f;
        #pragma unroll
        for (int nt=0;nt<4;nt++){
          int gc = n0 + wn + nt*16 + cl;
          if (gc < N) mx = fmaxf(mx, cvv[rt][nt][i]);
        }
        #pragma unroll
        for (int off=1; off<16; off<<=1) mx = fmaxf(mx, __shfl_xor(mx, off, 64));
        if (wn == 0 && cl == 0) rs[wm + rt*16 + rg + i] = mx;
        tsm[rt][i] = mx;
      }
    __syncthreads();
    if (wn != 0){
      #pragma unroll
      for (int rt=0;rt<4;rt++)
        #pragma unroll
        for (int i=0;i<4;i++){
          float c = fmaxf(tsm[rt][i], rs[wm + rt*16 + rg + i]);
          if (cl == 0) rs[wm + rt*16 + rg + i] = c;
        }
    }
    __syncthreads();
    #pragma unroll
    for (int rt=0;rt<4;rt++)
      #pragma unroll
      for (int i=0;i<4;i++){
        float rm = rs[wm + rt*16 + rg + i];
        float sm = 0.0f;
        #pragma unroll
        for (int nt=0;nt<4;nt++){
          int gc = n0 + wn + nt*16 + cl;
          if (gc < N) sm += __expf(cvv[rt][nt][i] - rm);
        }
        #pragma unroll
        for (int off=1; off<16; off<<=1) sm += __shfl_xor(sm, off, 64);
        tsm[rt][i] = sm;
        if (wn == 0 && cl == 0) rs2[wm + rt*16 + rg + i] = sm;
      }
    __syncthreads();
    if (wn != 0 && cl == 0){
      #pragma unroll
      for (int rt=0;rt<4;rt++)
        #pragma unroll
        for (int i=0;i<4;i++){
          int row = wm + rt*16 + rg + i;
          stats[(size_t)(m0 + row)*nblk + blockIdx.x] =
            make_float2(rs[row], tsm[rt][i] + rs2[row]);
        }
    }
  }

  __syncthreads();
  #pragma unroll
  for (int rt=0;rt<4;rt++)
    #pragma unroll
    for (int nt=0;nt<4;nt++)
      #pragma unroll
      for (int i=0;i<4;i++)
        CsF[(wm + rt*16 + rg + i)*132 + wn + nt*16 + cl] = cvv[rt][nt][i];
  __syncthreads();
  #pragma unroll
  for (int it=0; it<16; ++it){
    int row = (tid >> 5) + it*8;
    int c4 = tid & 31;
    int gc = n0 + c4*4;
    int gr = m0 + row;
    if (gc < N){
      float4 v = *reinterpret_cast<const float4*>(&CsF[row*132 + c4*4]);
      if (Cf) *reinterpret_cast<float4*>(Cf + (size_t)gr*ldc + gc) = v;
      if (Cbf){
        uint2 o;
        o.x = (unsigned)f2bf(v.x) | ((unsigned)f2bf(v.y) << 16);
        o.y = (unsigned)f2bf(v.z) | ((unsigned)f2bf(v.w) << 16);
        *reinterpret_cast<uint2*>(Cbf + (size_t)gr*ldc + gc) = o;
      }
    }
  }
}

// fallback f32 GEMM for W_v when ws too small
__global__ __launch_bounds__(256) void k_wv_f32(
  const float* __restrict__ Aah, const float* __restrict__ Wv, const float* __restrict__ bv,
  float* __restrict__ Cl)
{
  __shared__ float Asf[32][68];
  __shared__ float Bsf[32][64];
  int n0 = blockIdx.x*64, m0 = blockIdx.y*64;
  int tid = threadIdx.x;
  int tx = tid & 15, ty = tid >> 4;
  float acc[4][4] = {};
  for (int kc = 0; kc < H_; kc += 32){
    __syncthreads();
    #pragma unroll
    for (int i=0;i<8;i++){
      int e = i*256 + tid;
      Asf[e & 31][e >> 5] = Aah[(size_t)(m0 + (e >> 5))*H_ + kc + (e & 31)];
    }
    #pragma unroll
    for (int i=0;i<8;i++){
      int e = i*256 + tid;
      int nc = n0 + (e & 63); if (nc >= V_) nc = V_-1;
      Bsf[e >> 6][e & 63] = Wv[(size_t)(kc + (e >> 6))*V_ + nc];
    }
    __syncthreads();
    #pragma unroll
    for (int k=0;k<32;k++){
      float4 a4 = *reinterpret_cast<const float4*>(&Asf[k][ty*4]);
      float4 b4 = *reinterpret_cast<const float4*>(&Bsf[k][tx*4]);
      float av[4] = {a4.x, a4.y, a4.z, a4.w};
      float bv4[4] = {b4.x, b4.y, b4.z, b4.w};
      #pragma unroll
      for (int i=0;i<4;i++)
        #pragma unroll
        for (int j=0;j<4;j++)
          acc[i][j] = __builtin_fmaf(av[i], bv4[j], acc[i][j]);
    }
  }
  #pragma unroll
  for (int i=0;i<4;i++){
    int rr = m0 + ty*4 + i;
    #pragma unroll
    for (int j=0;j<4;j++){
      int cc = n0 + tx*4 + j;
      if (cc < V_) Cl[(size_t)rr*V_ + cc] = acc[i][j] + bv[cc];
    }
  }
}

// ---------------- persistent fused recurrence (register-blocked X, 1024 thr) ----------------
// iter i: X = [stage h_i; blocked gates_i (4 hl/thread, float4 W) + dec_{i-1} row;
//              kq-reduce; LSTM; publish] -> 1 hierarchical barrier ->
// Y = [read dec; 100 scores (16 warps); tag-spin 4-way stat exchange; softmax; attn/cov]
__global__ __launch_bounds__(1024) void k_recur(
  const float* __restrict__ W_hh, const float* __restrict__ G2,
  const float* __restrict__ W_decT, const u16* __restrict__ ep_bf,
  const float* __restrict__ w_cov, const float* __restrict__ v_att,
  const void* __restrict__ maskp, const float* __restrict__ h0,
  const float* __restrict__ c0, float* __restrict__ h_gT,
  float* __restrict__ dec_g, unsigned long long* __restrict__ mz,
  float* __restrict__ catbuf, float* __restrict__ attns, float* __restrict__ covs,
  unsigned* __restrict__ bar)
{
  const int beta = blockIdx.x;
  const int tid = threadIdx.x;
  __shared__ float h_lds[512*33];      // 67.6 KB, [k][b] padded
  __shared__ float W_l[16][512];       // 32 KB: 16 W_hh rows (row = g*4+hl)
  __shared__ float Wd_l[4][512];       // 8 KB: 4 W_decT rows
  __shared__ float gq[8][16][32];      // 16 KB: kq-partial gates
  __shared__ float pq[8][4][32];       // 4 KB: kq-partial dec
  __shared__ float gv2[16][32];        // 2 KB: reduced gates
  __shared__ float c_l[128];
  __shared__ float dec_l[512];
  __shared__ float sc_l[100];
  __shared__ float cov_l[100];
  __shared__ float smz[4][2];

  const int b32 = tid & 31;
  const int gg  = (tid >> 5) & 3;      // gate id (also dec row id)
  const int kq  = tid >> 7;            // 0..7: 64-k slice
  const int w = tid >> 6, l = tid & 63;
  const int grp = beta & 7;            // barrier arrival group
  const int bb = (beta & 7)*4 + (beta >> 5);
  const int sq = (beta >> 3) & 3;

  // one-time staging (reused across all 32 steps)
  for (int idx = tid; idx < 16*512; idx += 1024){
    int row = idx >> 9;
    int k = idx & 511;
    W_l[row][k] = W_hh[((size_t)(row >> 2)*H_ + beta*4 + (row & 3))*H_ + k];
  }
  for (int idx = tid; idx < 4*512; idx += 1024)
    Wd_l[idx >> 9][idx & 511] = W_decT[(size_t)(beta*4 + (idx >> 9))*H_ + (idx & 511)];
  if (tid < 128) c_l[tid] = c0[(size_t)(tid & 31)*H_ + beta*4 + (tid >> 5)];
  if (tid < 100) cov_l[tid] = 0.f;

  const unsigned* m32p = (const unsigned*)maskp;
  const unsigned char* m8p = (const unsigned char*)maskp;
  const bool bytemode = (m32p[0] == 0x01010101u);

  float wc8[8], va8[8];
  {
    int a0 = l*8;
    #pragma unroll
    for (int j=0;j<8;j++){ wc8[j] = w_cov[a0+j]; va8[j] = v_att[a0+j]; }
  }

  const float* Wg0 = &W_l[gg*4+0][0];
  const float* Wg1 = &W_l[gg*4+1][0];
  const float* Wg2 = &W_l[gg*4+2][0];
  const float* Wg3 = &W_l[gg*4+3][0];
  const float* Wdg = &Wd_l[gg][0];

  unsigned gen = 0;
  for (int i = 0; i <= T_; ++i){
    const int par = i & 1;
    // ---- X: stage h_i into LDS (coalesced) ----
    if (i == 0){
      #pragma unroll
      for (int j=0;j<16;j++){
        int flat = j*1024 + tid;                 // h0 layout [b][k]
        h_lds[(flat & 511)*33 + (flat >> 9)] = h0[flat];
      }
    } else {
      const float* hp = h_gT + (size_t)par*16384;   // layout [k][b]
      #pragma unroll
      for (int j=0;j<16;j++){
        int flat = j*1024 + tid;
        h_lds[(flat >> 5)*33 + (flat & 31)] = ALD(hp + flat);
      }
    }
    __syncthreads();

    // ---- blocked gates (4 hl) + dec (al=gg) over this thread's 64-k slice ----
    {
      float a0=0.f, a1=0.f, a2=0.f, a3=0.f, dd=0.f;
      const int k0 = kq*64;
      #pragma unroll 4
      for (int k4=0; k4<64; k4+=4){
        const int k = k0 + k4;
        float hv0 = h_lds[(k+0)*33 + b32];
        float hv1 = h_lds[(k+1)*33 + b32];
        float hv2 = h_lds[(k+2)*33 + b32];
        float hv3 = h_lds[(k+3)*33 + b32];
        float4 w0 = *reinterpret_cast<const float4*>(Wg0 + k);
        float4 w1 = *reinterpret_cast<const float4*>(Wg1 + k);
        float4 w2 = *reinterpret_cast<const float4*>(Wg2 + k);
        float4 w3 = *reinterpret_cast<const float4*>(Wg3 + k);
        float4 wd = *reinterpret_cast<const float4*>(Wdg + k);
        a0 = __builtin_fmaf(hv3,w0.w,__builtin_fmaf(hv2,w0.z,__builtin_fmaf(hv1,w0.y,__builtin_fmaf(hv0,w0.x,a0))));
        a1 = __builtin_fmaf(hv3,w1.w,__builtin_fmaf(hv2,w1.z,__builtin_fmaf(hv1,w1.y,__builtin_fmaf(hv0,w1.x,a1))));
        a2 = __builtin_fmaf(hv3,w2.w,__builtin_fmaf(hv2,w2.z,__builtin_fmaf(hv1,w2.y,__builtin_fmaf(hv0,w2.x,a2))));
        a3 = __builtin_fmaf(hv3,w3.w,__builtin_fmaf(hv2,w3.z,__builtin_fmaf(hv1,w3.y,__builtin_fmaf(hv0,w3.x,a3))));
        dd = __builtin_fmaf(hv3,wd.w,__builtin_fmaf(hv2,wd.z,__builtin_fmaf(hv1,wd.y,__builtin_fmaf(hv0,wd.x,dd))));
      }
      gq[kq][gg*4+0][b32] = a0;
      gq[kq][gg*4+1][b32] = a1;
      gq[kq][gg*4+2][b32] = a2;
      gq[kq][gg*4+3][b32] = a3;
      pq[kq][gg][b32] = dd;
    }
    __syncthreads();

    // ---- kq-reductions + publishes ----
    if (tid < 512){
      int row = tid >> 5, bq = tid & 31;
      float s = gq[0][row][bq]+gq[1][row][bq]+gq[2][row][bq]+gq[3][row][bq]
              + gq[4][row][bq]+gq[5][row][bq]+gq[6][row][bq]+gq[7][row][bq];
      gv2[row][bq] = s;
    } else if (i > 0 && tid < 640){
      int tt = tid - 512;
      int al = tt >> 5, bq = tt & 31;
      float d = pq[0][al][bq]+pq[1][al][bq]+pq[2][al][bq]+pq[3][al][bq]
              + pq[4][al][bq]+pq[5][al][bq]+pq[6][al][bq]+pq[7][al][bq];
      AST(dec_g + (size_t)par*B_*A_ + (size_t)bq*A_ + beta*4 + al, d);
    }
    __syncthreads();
    if (i < T_ && tid < 128){
      int hh = tid >> 5;
      int hidx = beta*4 + hh;
      const float* Gr = G2 + (size_t)i*65536 + (size_t)hidx*32 + b32;
      float gi = gv2[0*4+hh][b32] + Gr[0];
      float gf = gv2[1*4+hh][b32] + Gr[16384];
      float gz = gv2[2*4+hh][b32] + Gr[32768];
      float go = gv2[3*4+hh][b32] + Gr[49152];
      float co = c_l[tid];
      float cn = fsig(gf)*co + fsig(gi)*ftanh(gz);
      float hn = fsig(go)*ftanh(cn);
      c_l[tid] = cn;
      AST(h_gT + (size_t)(par^1)*16384 + (size_t)hidx*32 + b32, hn);
      catbuf[(size_t)(b32*T_ + i)*H3_ + H2_ + hidx] = hn;
    }
    gridbar2(bar, ++gen, grp);

    // ---- Y: scores_{i-1} for s-quarter sq of batch bb ----
    if (i > 0){
      const int r = bb*T_ + (i-1);
      if (tid < 512) dec_l[tid] = ALD(dec_g + (size_t)par*B_*A_ + (size_t)bb*A_ + tid);
      __syncthreads();
      int a0i = l*8;
      float dec8[8];
      #pragma unroll
      for (int j=0;j<8;j++) dec8[j] = dec_l[a0i+j];
      #pragma unroll
      for (int it=0; it<7; ++it){
        int sl = w + it*16;
        if (sl < 100){
          int s = sq*100 + sl;
          float cv = cov_l[sl];
          uint4 e8 = *reinterpret_cast<const uint4*>(ep_bf + (size_t)(bb*S_ + s)*A_ + a0i);
          unsigned uu[4] = {e8.x, e8.y, e8.z, e8.w};
          float part = 0.f;
          #pragma unroll
          for (int j=0;j<4;j++){
            float xa = bf2f((u16)(uu[j] & 0xFFFFu)) + dec8[2*j]   + cv*wc8[2*j];
            part += va8[2*j]*ftanh(xa);
            float xb = bf2f((u16)(uu[j] >> 16))     + dec8[2*j+1] + cv*wc8[2*j+1];
            part += va8[2*j+1]*ftanh(xb);
          }
          part = wsum(part);
          if (l == 0){
            bool on = bytemode ? (m8p[bb*S_+s] != 0) : (m32p[bb*S_+s] != 0u);
            sc_l[sl] = on ? part : -1e9f;
          }
        }
      }
      __syncthreads();
      // local (m,Z); publish with gen tag in Z low mantissa bits
      if (tid < 64){
        float x1v = sc_l[l];
        float x2v = (l + 64 < 100) ? sc_l[l + 64] : -1e30f;
        float m = wmax(fmaxf(x1v, x2v));
        float z = __expf(x1v - m) + ((l + 64 < 100) ? __expf(x2v - m) : 0.f);
        z = wsum(z);
        if (l == 0){
          unsigned zt = (__float_as_uint(z) & ~255u) | (gen & 255u);
          unsigned long long pk = ((unsigned long long)zt << 32) | (unsigned long long)__float_as_uint(m);
          AST(mz + bb*4 + sq, pk);
        }
      }
      if (tid < 4){
        unsigned long long v;
        do {
          v = ALD(mz + bb*4 + tid);
          if (((unsigned)(v >> 32) & 255u) == (gen & 255u)) break;
          __builtin_amdgcn_s_sleep(1);
        } while (true);
        smz[tid][0] = __uint_as_float((unsigned)v);
        smz[tid][1] = __uint_as_float((unsigned)(v >> 32));
      }
      __syncthreads();
      float gm = fmaxf(fmaxf(smz[0][0], smz[1][0]), fmaxf(smz[2][0], smz[3][0]));
      float gZ = smz[0][1]*__expf(smz[0][0]-gm) + smz[1][1]*__expf(smz[1][0]-gm)
               + smz[2][1]*__expf(smz[2][0]-gm) + smz[3][1]*__expf(smz[3][0]-gm);
      float invZ = 1.f/gZ;
      if (tid < 100){
        float av = __expf(sc_l[tid] - gm)*invZ;
        int s = sq*100 + tid;
        float cn = cov_l[tid] + av;
        cov_l[tid] = cn;
        attns[(size_t)r*S_ + s] = av;
        covs[(size_t)r*S_ + s]  = cn;
      }
      __syncthreads();
    }
  }
}

// ---------------- post-loop kernels ----------------

// context (deferred): catbuf[:, :1024] = attns @ enc   (fp32, single enc pass)
__global__ __launch_bounds__(256, 2) void k_ctx(
  const float* __restrict__ attns, const float* __restrict__ enc, float* __restrict__ catbuf)
{
  __shared__ float att_s[32][400];
  int d0 = blockIdx.x*64, b = blockIdx.y;
  int tid = threadIdx.x;
  for (int tt=0; tt<32; ++tt)
    for (int s = tid; s < S_; s += 256)
      att_s[tt][s] = attns[(size_t)(b*T_ + tt)*S_ + s];
  __syncthreads();
  int d = d0 + (tid & 63);
  int t0 = (tid >> 6)*8;
  float acc[8] = {0,0,0,0,0,0,0,0};
  const float* encb = enc + (size_t)b*S_*H2_ + d;
  #pragma unroll 4
  for (int s=0; s<S_; ++s){
    float ev = encb[(size_t)s*H2_];
    #pragma unroll
    for (int i=0;i<8;i++) acc[i] = __builtin_fmaf(att_s[t0+i][s], ev, acc[i]);
  }
  #pragma unroll
  for (int i=0;i<8;i++)
    catbuf[(size_t)(b*T_ + t0 + i)*H3_ + d] = acc[i];
}

// fp32 tiled GEMM: dec_states = tanh(catbuf @ W_ah + b_ah); optional bf16 copy
__global__ __launch_bounds__(256) void k_ahgemm(
  const float* __restrict__ Acat, const float* __restrict__ W_ah, const float* __restrict__ b_ah,
  float* __restrict__ dec_states, u16* __restrict__ ah_bf)
{
  __shared__ float Asf[32][68];
  __shared__ float Bsf[32][64];
  int n0 = blockIdx.x*64, m0 = blockIdx.y*64;
  int tid = threadIdx.x;
  int tx = tid & 15, ty = tid >> 4;
  float acc[4][4] = {};
  for (int kc = 0; kc < H3_; kc += 32){
    __syncthreads();
    #pragma unroll
    for (int i=0;i<8;i++){
      int e = i*256 + tid;
      Asf[e & 31][e >> 5] = Acat[(size_t)(m0 + (e >> 5))*H3_ + kc + (e & 31)];
    }
    #pragma unroll
    for (int i=0;i<8;i++){
      int e = i*256 + tid;
      Bsf[e >> 6][e & 63] = W_ah[(size_t)(kc + (e >> 6))*H_ + n0 + (e & 63)];
    }
    __syncthreads();
    #pragma unroll
    for (int k=0;k<32;k++){
      float4 a4 = *reinterpret_cast<const float4*>(&Asf[k][ty*4]);
      float4 b4 = *reinterpret_cast<const float4*>(&Bsf[k][tx*4]);
      float av[4] = {a4.x, a4.y, a4.z, a4.w};
      float bv[4] = {b4.x, b4.y, b4.z, b4.w};
      #pragma unroll
      for (int i=0;i<4;i++)
        #pragma unroll
        for (int j=0;j<4;j++)
          acc[i][j] = __builtin_fmaf(av[i], bv[j], acc[i][j]);
    }
  }
  #pragma unroll
  for (int i=0;i<4;i++){
    int rr = m0 + ty*4 + i;
    #pragma unroll
    for (int j=0;j<4;j++){
      int cc = n0 + tx*4 + j;
      float v = ftanh(acc[i][j] + b_ah[cc]);
      dec_states[(size_t)rr*H_ + cc] = v;
      if (ah_bf) ah_bf[(size_t)rr*H_ + cc] = f2bf(v);
    }
  }
}

__global__ __launch_bounds__(512) void k_pgen(const float* __restrict__ catbuf, const float* __restrict__ emb,
  const float* __restrict__ W_pg, const float* __restrict__ b_pg, float* __restrict__ pgens)
{
  int w = threadIdx.x >> 6, l = threadIdx.x & 63;
  int r = blockIdx.x*8 + w;
  float part = 0.0f;
  for (int d = l; d < PGK_; d += 64){
    float x = (d < H3_) ? catbuf[(size_t)r*H3_ + d] : emb[(size_t)r*E_ + (d - H3_)];
    part += x*W_pg[d];
  }
  part = wsum(part);
  if (l == 0) pgens[r] = fsig(part + b_pg[0]);
}

// per-row final: stats merge -> bitmask+hash scatter -> fast log transform
__global__ __launch_bounds__(512) void k_final2(
  float* __restrict__ logits, const float* __restrict__ pgens,
  const float* __restrict__ attns, const int* __restrict__ src,
  const float2* __restrict__ stats, int nblk)
{
  __shared__ unsigned bits[1568];
  __shared__ unsigned keys[1024];
  __shared__ float vals[1024];
  __shared__ float sred[18];
  int r = blockIdx.x;
  int b = r >> 5;
  int tid = threadIdx.x;
  int w = tid >> 6, l = tid & 63;
  float* row = logits + (size_t)r*V_;

  for (int i = tid; i < 1568; i += 512) bits[i] = 0u;
  for (int i = tid; i < 1024; i += 512){ keys[i] = 0xFFFFFFFFu; vals[i] = 0.0f; }

  if (stats){
    float m = -1e30f, Z = 0.0f;
    if (tid < nblk){ float2 st = stats[(size_t)r*nblk + tid]; m = st.x; Z = st.y; }
    #pragma unroll
    for (int off=32; off>0; off>>=1){
      float mo = __shfl_xor(m, off, 64);
      float Zo = __shfl_xor(Z, off, 64);
      float nm = fmaxf(m, mo);
      Z = Z*__expf(m - nm) + Zo*__expf(mo - nm);
      m = nm;
    }
    if (l == 0){ sred[w*2] = m; sred[w*2+1] = Z; }
    __syncthreads();
    if (tid == 0){
      float gm = -1e30f, gz = 0.0f;
      #pragma unroll
      for (int i=0;i<8;i++){
        float mi = sred[i*2], zi = sred[i*2+1];
        float nm = fmaxf(gm, mi);
        gz = gz*__expf(gm - nm) + zi*__expf(mi - nm);
        gm = nm;
      }
      sred[16] = gm; sred[17] = gz;
    }
    __syncthreads();
  } else {
    float m = -1e30f;
    for (int j = tid; j < V_/4; j += 512){
      float4 x = reinterpret_cast<const float4*>(row)[j];
      m = fmaxf(fmaxf(m, x.x), fmaxf(fmaxf(x.y, x.z), x.w));
    }
    m = wmax(m);
    if (l == 0) sred[w] = m;
    __syncthreads();
    if (tid == 0){
      float gm = -1e30f;
      #pragma unroll
      for (int i=0;i<8;i++) gm = fmaxf(gm, sred[i]);
      sred[16] = gm;
    }
    __syncthreads();
    float gm = sred[16];
    float z = 0.0f;
    for (int j = tid; j < V_/4; j += 512){
      float4 x = reinterpret_cast<const float4*>(row)[j];
      z += __expf(x.x-gm) + __expf(x.y-gm) + __expf(x.z-gm) + __expf(x.w-gm);
    }
    z = wsum(z);
    if (l == 0) sred[8 + w] = z;
    __syncthreads();
    if (tid == 0){
      float gz = 0.0f;
      #pragma unroll
      for (int i=0;i<8;i++) gz += sred[8 + i];
      sred[17] = gz;
    }
    __syncthreads();
  }

  float gm = sred[16];
  float gZ = sred[17];
  float pg = pgens[r];
  float scale = pg / gZ;
  float lscale = __logf(scale);

  if (tid < S_){
    int tok = src[b*S_ + tid];
    float add = (1.0f - pg)*attns[(size_t)r*S_ + tid];
    atomicOr(&bits[tok >> 5], 1u << (tok & 31));
    unsigned h = ((unsigned)tok * 2654435761u) >> 22;
    while (true){
      unsigned prev = atomicCAS(&keys[h], 0xFFFFFFFFu, (unsigned)tok);
      if (prev == 0xFFFFFFFFu || prev == (unsigned)tok){
        atomicAdd(&vals[h], add);
        break;
      }
      h = (h + 1) & 1023;
    }
  }
  __syncthreads();

  for (int j = tid; j < V_/4; j += 512){
    float4 x = reinterpret_cast<const float4*>(row)[j];
    int v = 4*j;
    float o[4];
    float xv[4] = {x.x, x.y, x.z, x.w};
    #pragma unroll
    for (int k=0;k<4;k++){
      int vv = v + k;
      bool hit = (bits[vv >> 5] >> (vv & 31)) & 1u;
      float tt = xv[k] - gm + lscale;
      if (!hit && tt > -25.0f){
        o[k] = tt;
      } else {
        float pval = __expf(xv[k] - gm)*scale;
        if (hit){
          unsigned h = ((unsigned)vv * 2654435761u) >> 22;
          while (keys[h] != 0xFFFFFFFFu){
            if (keys[h] == (unsigned)vv){ pval += vals[h]; break; }
            h = (h + 1) & 1023;
          }
        }
        o[k] = __logf(pval + 1e-20f);
      }
    }
    reinterpret_cast<float4*>(row)[j] = make_float4(o[0], o[1], o[2], o[3]);
  }
}

// ---------------- host ----------------

extern "C" void kernel_launch(void* const* d_in, const int* in_sizes, int n_in,
                              void* d_out, int out_size, void* d_ws, size_t ws_size,
                              hipStream_t stream)
{
  const int* src_tokens = (const int*)d_in[0];
  const float* embedded = (const float*)d_in[1];
  const float* enc      = (const float*)d_in[2];
  const void*  maskp    = (const void*)d_in[3];
  const float* h0  = (const float*)d_in[4];
  const float* c0  = (const float*)d_in[5];
  const float* W_ih = (const float*)d_in[6];
  const float* W_hh = (const float*)d_in[7];
  const float* b_ih = (const float*)d_in[8];
  const float* b_hh = (const float*)d_in[9];
  const float* W_enc = (const float*)d_in[10];
  const float* W_dec = (const float*)d_in[11];
  const float* w_cov = (const float*)d_in[12];
  const float* b_att = (const float*)d_in[13];
  const float* v_att = (const float*)d_in[14];
  const float* W_ah  = (const float*)d_in[15];
  const float* b_ah  = (const float*)d_in[16];
  const float* W_pg  = (const float*)d_in[17];
  const float* b_pg  = (const float*)d_in[18];
  const float* W_v   = (const float*)d_in[19];
  const float* b_v   = (const float*)d_in[20];
  (void)in_sizes; (void)n_in; (void)out_size;

  float* outp = (float*)d_out;
  float* logps = outp;                                  // (B,T,V)   204.8 MB
  float* dec_states = logps + (size_t)R_*V_;            // (B,T,H)
  float* attns = dec_states + (size_t)R_*H_;            // (B,T,S)
  float* covs  = attns + (size_t)R_*S_;                 // (B,T,S)
  float* pgens = covs + (size_t)R_*S_;                  // (B,T)

  // big transients live INSIDE the logps output region (dead until W_v GEMM)
  char* sp = (char*)logps;
  auto salloc = [&](size_t bytes) -> void* {
    void* p = (void*)sp;
    sp += (bytes + 255) & ~(size_t)255;
    return p;
  };
  unsigned* bar = (unsigned*)salloc(2048);
  unsigned long long* mz = (unsigned long long*)salloc((size_t)B_*4*8);
  u16* ep_bf    = (u16*)salloc((size_t)B_*S_*A_*2);        // 13.1 MB
  u16* enc3     = (u16*)salloc((size_t)B_*S_*3072*2);      // 78.6 MB
  u16* WencT3   = (u16*)salloc((size_t)A_*3072*2);         // 3.1 MB
  float* WihT   = (float*)salloc((size_t)E_*H4_*4);        // 1 MB
  float* W_decT = (float*)salloc((size_t)H_*A_*4);         // 1 MB
  float* G2     = (float*)salloc((size_t)R_*H4_*4);        // 8.4 MB [t][g][hidx][b]
  float* catbuf = (float*)salloc((size_t)R_*H3_*4);        // 6.3 MB [context | h]
  float* dec_g  = (float*)salloc((size_t)2*B_*A_*4);       // 128 KB double-buffered
  float* h_gT   = (float*)salloc((size_t)2*H_*B_*4);       // 128 KB double-buffered [k][b]
  // total ~112 MB < 204.8 MB -- all consumed before W_v GEMM writes logps

  // d_ws: only buffers live WHILE logps is being written
  char* wp = (char*)d_ws;
  auto walloc = [&](size_t bytes) -> void* {
    void* p = (void*)wp;
    wp += (bytes + 255) & ~(size_t)255;
    return p;
  };
  u16* ah_bf = (u16*)walloc((size_t)R_*H_*2);              // 1.05 MB
  u16* WvT   = (u16*)walloc((size_t)V_*H_*2);              // 51.2 MB
  float2* stats = (float2*)walloc((size_t)R_*NBLKV_*8);    // 3.2 MB
  const size_t ws_fast  = (size_t)R_*H_*2 + (size_t)V_*H_*2 + 512;
  const size_t ws_stats = ws_fast + (size_t)R_*NBLKV_*8 + 256;
  const bool fast_wv   = (ws_size >= ws_fast);
  const bool use_stats = (ws_size >= ws_stats);

  // setup
  k_init0<<<1, 512, 0, stream>>>(bar, mz);
  k_transpose<<<dim3(2,32), 256, 0, stream>>>(W_ih, WihT, H4_, E_);
  k_transpose<<<dim3(8,8), 256, 0, stream>>>(W_dec, W_decT, H_, A_);
  k_gih<<<128, 256, 0, stream>>>(embedded, WihT, b_ih, b_hh, G2);
  k_conv3<<<(B_*S_*H2_/4 + 255)/256, 256, 0, stream>>>(enc, enc3, B_*S_*H2_/4);
  k_convT3<<<dim3(8,16), 256, 0, stream>>>(W_enc, WencT3);
  if (fast_wv)
    k_convT<<<dim3((V_+63)/64, 8), 256, 0, stream>>>(W_v, WvT, H_, V_);

  // enc_proj: single split-bf16 GEMM (K=3072), bf16 output + b_att
  k_gemm_bf16<<<dim3(A_/128, (B_*S_)/128), 256, 0, stream>>>(
      enc3, 3072, WencT3, 3072, b_att, nullptr, ep_bf, A_, B_*S_, A_, 3072, nullptr, 0);

  // fused persistent recurrence (register-blocked, 1024 threads)
  k_recur<<<GRB_, 1024, 0, stream>>>(W_hh, G2, W_decT, ep_bf, w_cov, v_att, maskp,
                                     h0, c0, h_gT, dec_g, mz,
                                     catbuf, attns, covs, bar);

  // deferred contexts + batched tail
  k_ctx<<<dim3(16, 32), 256, 0, stream>>>(attns, enc, catbuf);
  k_ahgemm<<<dim3(8,16), 256, 0, stream>>>(catbuf, W_ah, b_ah, dec_states, fast_wv ? ah_bf : (u16*)nullptr);
  k_pgen<<<128, 512, 0, stream>>>(catbuf, embedded, W_pg, b_pg, pgens);

  // logits
  if (fast_wv)
    k_gemm_bf16<<<dim3(NBLKV_, R_/128), 256, 0, stream>>>(
        ah_bf, H_, WvT, H_, b_v, logps, nullptr, V_, R_, V_, H_,
        use_stats ? stats : nullptr, NBLKV_);
  else
    k_wv_f32<<<dim3((V_+63)/64, R_/64), 256, 0, stream>>>(dec_states, W_v, b_v, logps);

  k_final2<<<R_, 512, 0, stream>>>(logps, pgens, attns, src_tokens,
                                   (fast_wv && use_stats) ? stats : nullptr, NBLKV_);
}

// Round 9
// 1192.722 us; speedup vs baseline: 2.1939x; 1.1826x over previous
//
#include <hip/hip_runtime.h>
#include <hip/hip_bf16.h>
#include <stdint.h>
#include <stddef.h>

#define B_  32
#define S_  400
#define T_  32
#define H_  512
#define E_  128
#define V_  50000
#define A_  512
#define H2_ 1024
#define H3_ 1536
#define H4_ 2048
#define R_  1024     // B*T
#define PGK_ 1664    // 3H+E
#define NBLKV_ 391   // ceil(V/128)
#define GRB_ 128     // persistent-recurrence grid
#define WROW_ 520    // u16 row stride for LDS bf16 tiles (16B-aligned)

typedef unsigned short u16;
typedef short v8s __attribute__((ext_vector_type(8)));
typedef float v4f __attribute__((ext_vector_type(4)));

__device__ __forceinline__ float fsig(float x){ return 1.0f/(1.0f + __expf(-x)); }
__device__ __forceinline__ float ftanh(float x){ float e = __expf(2.0f*x); return 1.0f - 2.0f/(e + 1.0f); }
__device__ __forceinline__ u16 f2bf(float x){ __hip_bfloat16 b = __float2bfloat16(x); return *reinterpret_cast<u16*>(&b); }
__device__ __forceinline__ float bf2f(u16 u){ __hip_bfloat16 b = *reinterpret_cast<__hip_bfloat16*>(&u); return __bfloat162float(b); }

__device__ __forceinline__ float wsum(float v){
  #pragma unroll
  for (int off = 32; off > 0; off >>= 1) v += __shfl_xor(v, off, 64);
  return v;
}
__device__ __forceinline__ float wmax(float v){
  #pragma unroll
  for (int off = 32; off > 0; off >>= 1) v = fmaxf(v, __shfl_xor(v, off, 64));
  return v;
}

#define ALD(p)    __hip_atomic_load((p), __ATOMIC_RELAXED, __HIP_MEMORY_SCOPE_AGENT)
#define AST(p,v)  __hip_atomic_store((p), (v), __ATOMIC_RELAXED, __HIP_MEMORY_SCOPE_AGENT)

// LDS-only barrier: waits lgkmcnt (LDS) but leaves vmem (prefetch) in flight.
__device__ __forceinline__ void ldsbar(){
  asm volatile("s_waitcnt lgkmcnt(0)" ::: "memory");
  __builtin_amdgcn_s_barrier();
  asm volatile("" ::: "memory");
}

// hierarchical fence-free grid barrier: 8 spread counters (16 arrivals each,
// keyed by beta&7) -> 1 global counter (8 arrivals) -> gate. Monotonic counts.
__device__ __forceinline__ void gridbar2(unsigned* bar, unsigned target, int grp){
  __syncthreads();
  if (threadIdx.x == 0){
    unsigned v = __hip_atomic_fetch_add(bar + grp*32, 1u, __ATOMIC_RELAXED, __HIP_MEMORY_SCOPE_AGENT);
    if (v == target*16u - 1u){
      unsigned g2 = __hip_atomic_fetch_add(bar + 256, 1u, __ATOMIC_RELAXED, __HIP_MEMORY_SCOPE_AGENT);
      if (g2 == target*8u - 1u)
        AST(bar + 288, target);
    }
    while (ALD(bar + 288) < target) __builtin_amdgcn_s_sleep(2);
    asm volatile("" ::: "memory");
  }
  __syncthreads();
}

// ---------------- setup kernels ----------------

__global__ void k_init0(unsigned* __restrict__ bar, unsigned long long* __restrict__ mz){
  int t = threadIdx.x;
  if (t < 512) AST(bar + t, 0u);
  if (t < 128) AST(mz + t, 0ull);
}

__global__ __launch_bounds__(256) void k_transpose(const float* __restrict__ in, float* __restrict__ out, int R, int C){
  __shared__ float tile[64][65];
  int c0 = blockIdx.x*64, r0 = blockIdx.y*64;
  int tid = threadIdx.x;
  int cl = tid & 63, q = tid >> 6;
  #pragma unroll
  for (int i=0;i<16;i++){
    int r = q + i*4;
    float v = 0.0f;
    if (r0 + r < R && c0 + cl < C) v = in[(size_t)(r0+r)*C + c0 + cl];
    tile[r][cl] = v;
  }
  __syncthreads();
  #pragma unroll
  for (int i=0;i<16;i++){
    int c = q + i*4;
    if (c0 + c < C && r0 + cl < R)
      out[(size_t)(c0+c)*R + r0 + cl] = tile[cl][c];
  }
}

// f32 [R][C] -> bf16 [C][R] (hi only; used for W_v)
__global__ __launch_bounds__(256) void k_convT(const float* __restrict__ in, u16* __restrict__ hi, int R, int C){
  __shared__ float tile[64][65];
  int c0 = blockIdx.x*64, r0 = blockIdx.y*64;
  int tid = threadIdx.x;
  int cl = tid & 63, q = tid >> 6;
  #pragma unroll
  for (int i=0;i<16;i++){
    int r = q + i*4;
    float v = 0.0f;
    if (r0 + r < R && c0 + cl < C) v = in[(size_t)(r0+r)*C + c0 + cl];
    tile[r][cl] = v;
  }
  __syncthreads();
  #pragma unroll
  for (int i=0;i<16;i++){
    int c = q + i*4;
    if (c0 + c < C && r0 + cl < R)
      hi[(size_t)(c0+c)*R + r0 + cl] = f2bf(tile[cl][c]);
  }
}

// W_enc [1024][512] f32 -> WencT3 [512][3072] bf16 rows = [hi | lo | hi]
__global__ __launch_bounds__(256) void k_convT3(const float* __restrict__ in, u16* __restrict__ out){
  __shared__ float tile[64][65];
  int c0 = blockIdx.x*64, r0 = blockIdx.y*64;   // grid (8,16)
  int tid = threadIdx.x;
  int cl = tid & 63, q = tid >> 6;
  #pragma unroll
  for (int i=0;i<16;i++){
    int r = q + i*4;
    tile[r][cl] = in[(size_t)(r0+r)*A_ + c0 + cl];
  }
  __syncthreads();
  #pragma unroll
  for (int i=0;i<16;i++){
    int c = q + i*4;
    float v = tile[cl][c];
    u16 h = f2bf(v);
    u16 lo = f2bf(v - bf2f(h));
    size_t o = (size_t)(c0+c)*3072 + (r0+cl);
    out[o] = h;
    out[o + 1024] = lo;
    out[o + 2048] = h;
  }
}

// enc [12800][1024] f32 -> enc3 [12800][3072] bf16 rows = [hi | hi | lo]
__global__ void k_conv3(const float* __restrict__ in, u16* __restrict__ out, int n4){
  int i = blockIdx.x*256 + threadIdx.x;
  if (i >= n4) return;
  float4 x = reinterpret_cast<const float4*>(in)[i];
  u16 h0v=f2bf(x.x), h1v=f2bf(x.y), h2v=f2bf(x.z), h3v=f2bf(x.w);
  uint2 hv; hv.x = (unsigned)h0v | ((unsigned)h1v << 16); hv.y = (unsigned)h2v | ((unsigned)h3v << 16);
  uint2 lv;
  lv.x = (unsigned)f2bf(x.x - bf2f(h0v)) | ((unsigned)f2bf(x.y - bf2f(h1v)) << 16);
  lv.y = (unsigned)f2bf(x.z - bf2f(h2v)) | ((unsigned)f2bf(x.w - bf2f(h3v)) << 16);
  int row = i >> 8, c = (i & 255)*4;
  size_t base = (size_t)row*3072 + c;
  *reinterpret_cast<uint2*>(out + base)        = hv;
  *reinterpret_cast<uint2*>(out + base + 1024) = hv;
  *reinterpret_cast<uint2*>(out + base + 2048) = lv;
}

// G2[t][g][hidx][b] = b_ih + b_hh + emb @ W_ih^T   (layout for k_recur coalesced reads)
__global__ __launch_bounds__(256) void k_gih(const float* __restrict__ emb, const float* __restrict__ WihT,
    const float* __restrict__ b_ih, const float* __restrict__ b_hh, float* __restrict__ G){
  __shared__ float em[8][128];
  int r0 = blockIdx.x*8;
  int tid = threadIdx.x;
  #pragma unroll
  for (int i=0;i<4;i++){
    int e = i*256 + tid;
    em[e>>7][e&127] = emb[(size_t)(r0 + (e>>7))*E_ + (e&127)];
  }
  __syncthreads();
  for (int jj=0;jj<8;jj++){
    int j = jj*256 + tid;
    float bias = b_ih[j] + b_hh[j];
    float acc[8];
    #pragma unroll
    for (int r=0;r<8;r++) acc[r] = bias;
    for (int e=0;e<128;e++){
      float wv = WihT[(size_t)e*H4_ + j];
      #pragma unroll
      for (int r=0;r<8;r++) acc[r] += em[r][e]*wv;
    }
    #pragma unroll
    for (int rr=0;rr<8;rr++){
      int r = r0 + rr;
      G[(size_t)(r & 31)*65536 + (size_t)(j >> 9)*16384 + (size_t)(j & 511)*32 + (r >> 5)] = acc[rr];
    }
  }
}

// ---------------- MFMA bf16 GEMM (coalesced LDS epilogue, optional stats) ----------------
__global__ __launch_bounds__(256, 2) void k_gemm_bf16(
    const u16* __restrict__ A, int lda, const u16* __restrict__ Bt, int ldb,
    const float* __restrict__ bias, float* __restrict__ Cf, u16* __restrict__ Cbf, int ldc,
    int M, int N, int K, float2* __restrict__ stats, int nblk)
{
  __shared__ __align__(16) float CsF[128*132];
  __shared__ float rs[128], rs2[128];
  u16* As = reinterpret_cast<u16*>(CsF);
  u16* Bs = As + 128*64;
  const int tid = threadIdx.x;
  const int m0 = blockIdx.y * 128;
  const int n0 = blockIdx.x * 128;
  const int l  = tid & 63;
  const int wavebase = tid & ~63;
  const int wid = tid >> 6;
  const int wm = (wid >> 1) * 64;
  const int wn = (wid & 1) * 64;

  v4f acc[4][4];
  v4f vzero = {0.0f, 0.0f, 0.0f, 0.0f};
  #pragma unroll
  for (int i=0;i<4;i++)
    #pragma unroll
    for (int j=0;j<4;j++) acc[i][j] = vzero;

  for (int k0 = 0; k0 < K; k0 += 64){
    __syncthreads();
    #pragma unroll
    for (int jj=0;jj<4;jj++){
      int fc = jj*256 + tid;
      int row = fc >> 3;
      int cc = (fc & 7) ^ (row & 7);
      const u16* g = A + (size_t)(m0 + row)*lda + k0 + cc*8;
      __builtin_amdgcn_global_load_lds(
        (__attribute__((address_space(1))) void*)g,
        (__attribute__((address_space(3))) void*)(As + (size_t)(jj*256 + wavebase)*8),
        16, 0, 0);
    }
    #pragma unroll
    for (int jj=0;jj<4;jj++){
      int fc = jj*256 + tid;
      int row = fc >> 3;
      int cc = (fc & 7) ^ (row & 7);
      int rn = n0 + row; if (rn > N-1) rn = N-1;
      const u16* g = Bt + (size_t)rn*ldb + k0 + cc*8;
      __builtin_amdgcn_global_load_lds(
        (__attribute__((address_space(1))) void*)g,
        (__attribute__((address_space(3))) void*)(Bs + (size_t)(jj*256 + wavebase)*8),
        16, 0, 0);
    }
    __syncthreads();
    #pragma unroll
    for (int ks=0;ks<2;ks++){
      v8s af[4], bfr[4];
      #pragma unroll
      for (int rt=0;rt<4;rt++){
        int r = wm + rt*16 + (l & 15);
        int cs = (ks*4 + (l >> 4)) ^ (r & 7);
        af[rt] = *reinterpret_cast<const v8s*>(As + r*64 + cs*8);
      }
      #pragma unroll
      for (int nt=0;nt<4;nt++){
        int r = wn + nt*16 + (l & 15);
        int cs = (ks*4 + (l >> 4)) ^ (r & 7);
        bfr[nt] = *reinterpret_cast<const v8s*>(Bs + r*64 + cs*8);
      }
      #pragma unroll
      for (int rt=0;rt<4;rt++)
        #pragma unroll
        for (int nt=0;nt<4;nt++)
          acc[rt][nt] = __builtin_amdgcn_mfma_f32_16x16x32_bf16(af[rt], bfr[nt], acc[rt][nt], 0, 0, 0);
    }
  }

  const int cl = l & 15;
  const int rg = (l >> 4) * 4;
  float cvv[4][4][4];
  #pragma unroll
  for (int rt=0;rt<4;rt++)
    #pragma unroll
    for (int nt=0;nt<4;nt++){
      int gc = n0 + wn + nt*16 + cl;
      float bv = (bias && gc < N) ? bias[gc] : 0.0f;
      #pragma unroll
      for (int i=0;i<4;i++) cvv[rt][nt][i] = acc[rt][nt][i] + bv;
    }

  if (stats){
    float tsm[4][4];
    #pragma unroll
    for (int rt=0;rt<4;rt++)
      #pragma unroll
      for (int i=0;i<4;i++){
        float mx = -1e30f;
        #pragma unroll
        for (int nt=0;nt<4;nt++){
          int gc = n0 + wn + nt*16 + cl;
          if (gc < N) mx = fmaxf(mx, cvv[rt][nt][i]);
        }
        #pragma unroll
        for (int off=1; off<16; off<<=1) mx = fmaxf(mx, __shfl_xor(mx, off, 64));
        if (wn == 0 && cl == 0) rs[wm + rt*16 + rg + i] = mx;
        tsm[rt][i] = mx;
      }
    __syncthreads();
    if (wn != 0){
      #pragma unroll
      for (int rt=0;rt<4;rt++)
        #pragma unroll
        for (int i=0;i<4;i++){
          float c = fmaxf(tsm[rt][i], rs[wm + rt*16 + rg + i]);
          if (cl == 0) rs[wm + rt*16 + rg + i] = c;
        }
    }
    __syncthreads();
    #pragma unroll
    for (int rt=0;rt<4;rt++)
      #pragma unroll
      for (int i=0;i<4;i++){
        float rm = rs[wm + rt*16 + rg + i];
        float sm = 0.0f;
        #pragma unroll
        for (int nt=0;nt<4;nt++){
          int gc = n0 + wn + nt*16 + cl;
          if (gc < N) sm += __expf(cvv[rt][nt][i] - rm);
        }
        #pragma unroll
        for (int off=1; off<16; off<<=1) sm += __shfl_xor(sm, off, 64);
        tsm[rt][i] = sm;
        if (wn == 0 && cl == 0) rs2[wm + rt*16 + rg + i] = sm;
      }
    __syncthreads();
    if (wn != 0 && cl == 0){
      #pragma unroll
      for (int rt=0;rt<4;rt++)
        #pragma unroll
        for (int i=0;i<4;i++){
          int row = wm + rt*16 + rg + i;
          stats[(size_t)(m0 + row)*nblk + blockIdx.x] =
            make_float2(rs[row], tsm[rt][i] + rs2[row]);
        }
    }
  }

  __syncthreads();
  #pragma unroll
  for (int rt=0;rt<4;rt++)
    #pragma unroll
    for (int nt=0;nt<4;nt++)
      #pragma unroll
      for (int i=0;i<4;i++)
        CsF[(wm + rt*16 + rg + i)*132 + wn + nt*16 + cl] = cvv[rt][nt][i];
  __syncthreads();
  #pragma unroll
  for (int it=0; it<16; ++it){
    int row = (tid >> 5) + it*8;
    int c4 = tid & 31;
    int gc = n0 + c4*4;
    int gr = m0 + row;
    if (gc < N){
      float4 v = *reinterpret_cast<const float4*>(&CsF[row*132 + c4*4]);
      if (Cf) *reinterpret_cast<float4*>(Cf + (size_t)gr*ldc + gc) = v;
      if (Cbf){
        uint2 o;
        o.x = (unsigned)f2bf(v.x) | ((unsigned)f2bf(v.y) << 16);
        o.y = (unsigned)f2bf(v.z) | ((unsigned)f2bf(v.w) << 16);
        *reinterpret_cast<uint2*>(Cbf + (size_t)gr*ldc + gc) = o;
      }
    }
  }
}

// fallback f32 GEMM for W_v when ws too small
__global__ __launch_bounds__(256) void k_wv_f32(
  const float* __restrict__ Aah, const float* __restrict__ Wv, const float* __restrict__ bv,
  float* __restrict__ Cl)
{
  __shared__ float Asf[32][68];
  __shared__ float Bsf[32][64];
  int n0 = blockIdx.x*64, m0 = blockIdx.y*64;
  int tid = threadIdx.x;
  int tx = tid & 15, ty = tid >> 4;
  float acc[4][4] = {};
  for (int kc = 0; kc < H_; kc += 32){
    __syncthreads();
    #pragma unroll
    for (int i=0;i<8;i++){
      int e = i*256 + tid;
      Asf[e & 31][e >> 5] = Aah[(size_t)(m0 + (e >> 5))*H_ + kc + (e & 31)];
    }
    #pragma unroll
    for (int i=0;i<8;i++){
      int e = i*256 + tid;
      int nc = n0 + (e & 63); if (nc >= V_) nc = V_-1;
      Bsf[e >> 6][e & 63] = Wv[(size_t)(kc + (e >> 6))*V_ + nc];
    }
    __syncthreads();
    #pragma unroll
    for (int k=0;k<32;k++){
      float4 a4 = *reinterpret_cast<const float4*>(&Asf[k][ty*4]);
      float4 b4 = *reinterpret_cast<const float4*>(&Bsf[k][tx*4]);
      float av[4] = {a4.x, a4.y, a4.z, a4.w};
      float bv4[4] = {b4.x, b4.y, b4.z, b4.w};
      #pragma unroll
      for (int i=0;i<4;i++)
        #pragma unroll
        for (int j=0;j<4;j++)
          acc[i][j] = __builtin_fmaf(av[i], bv4[j], acc[i][j]);
    }
  }
  #pragma unroll
  for (int i=0;i<4;i++){
    int rr = m0 + ty*4 + i;
    #pragma unroll
    for (int j=0;j<4;j++){
      int cc = n0 + tx*4 + j;
      if (cc < V_) Cl[(size_t)rr*V_ + cc] = acc[i][j] + bv[cc];
    }
  }
}

// ---------------- persistent fused recurrence (MFMA X-phase) ----------------
// iter i: [cvt h->bf16 hi/lo LDS] ldsbar [4 waves: 3-pass split-bf16 MFMA
// (20x32x512) -> gv2 + dec publish] ldsbar [LSTM -> publish h] gridbar
// [prefetch h_{i+1} regs] [Y: scores_{i-1}, tag-spin stats, softmax, attn/cov]
__global__ __launch_bounds__(1024) void k_recur(
  const float* __restrict__ W_hh, const float* __restrict__ G2,
  const float* __restrict__ W_decT, const u16* __restrict__ ep_bf,
  const float* __restrict__ w_cov, const float* __restrict__ v_att,
  const void* __restrict__ maskp, const float* __restrict__ h0,
  const float* __restrict__ c0, float* __restrict__ h_gT,
  float* __restrict__ dec_g, unsigned long long* __restrict__ mz,
  float* __restrict__ catbuf, float* __restrict__ attns, float* __restrict__ covs,
  unsigned* __restrict__ bar)
{
  const int beta = blockIdx.x;
  const int tid = threadIdx.x;
  __shared__ __align__(16) u16 Whi[32*WROW_];   // 33.3 KB (rows: 16 gate, 4 dec, 12 zero)
  __shared__ __align__(16) u16 Wlo[32*WROW_];
  __shared__ __align__(16) u16 Hhi[32*WROW_];   // [b][k] bf16
  __shared__ __align__(16) u16 Hlo[32*WROW_];
  __shared__ float gv2[16][32];
  __shared__ float c_l[128];
  __shared__ float dec_l[512];
  __shared__ float sc_l[100];
  __shared__ float cov_l[100];
  __shared__ float smz[4][2];

  const int b32 = tid & 31;
  const int w = tid >> 6, l = tid & 63;
  const int grp = beta & 7;            // barrier arrival group
  const int bb = (beta & 7)*4 + (beta >> 5);
  const int sq = (beta >> 3) & 3;
  const int b2 = (tid & 15)*2;         // cvt/prefetch: batch pair
  const int kg = tid >> 4;             // cvt/prefetch: k-octet 0..63

  // one-time staging: W rows (16 gates + 4 dec + 12 zero) as bf16 hi/lo
  for (int idx = tid; idx < 32*512; idx += 1024){
    int row = idx >> 9;
    int k = idx & 511;
    float v = 0.0f;
    if (row < 16)      v = W_hh[((size_t)(row >> 2)*H_ + beta*4 + (row & 3))*H_ + k];
    else if (row < 20) v = W_decT[(size_t)(beta*4 + (row - 16))*H_ + k];
    u16 h = f2bf(v);
    Whi[row*WROW_ + k] = h;
    Wlo[row*WROW_ + k] = f2bf(v - bf2f(h));
  }
  if (tid < 128) c_l[tid] = c0[(size_t)(tid & 31)*H_ + beta*4 + (tid >> 5)];
  if (tid < 100) cov_l[tid] = 0.f;

  const unsigned* m32p = (const unsigned*)maskp;
  const unsigned char* m8p = (const unsigned char*)maskp;
  const bool bytemode = (m32p[0] == 0x01010101u);

  float wc8[8], va8[8];
  {
    int a0 = l*8;
    #pragma unroll
    for (int j=0;j<8;j++){ wc8[j] = w_cov[a0+j]; va8[j] = v_att[a0+j]; }
  }

  // prologue: h_state[0] from h0 ([b][k] layout)
  float hA[8], hB[8];
  unsigned long long hld[8];
  #pragma unroll
  for (int kk=0;kk<8;kk++){
    int k = kg*8 + kk;
    hA[kk] = h0[(size_t)b2*H_ + k];
    hB[kk] = h0[(size_t)(b2+1)*H_ + k];
  }

  unsigned gen = 0;
  for (int i = 0; i <= T_; ++i){
    const int par = i & 1;
    // ---- cvt h -> bf16 hi/lo, write [b][k] rows ----
    {
      v8s phA, plA, phB, plB;
      #pragma unroll
      for (int kk=0;kk<8;kk++){
        float va = hA[kk], vb = hB[kk];
        u16 ha = f2bf(va), hb = f2bf(vb);
        phA[kk] = (short)ha; plA[kk] = (short)f2bf(va - bf2f(ha));
        phB[kk] = (short)hb; plB[kk] = (short)f2bf(vb - bf2f(hb));
      }
      *reinterpret_cast<v8s*>(Hhi + (size_t)b2*WROW_ + kg*8) = phA;
      *reinterpret_cast<v8s*>(Hlo + (size_t)b2*WROW_ + kg*8) = plA;
      *reinterpret_cast<v8s*>(Hhi + (size_t)(b2+1)*WROW_ + kg*8) = phB;
      *reinterpret_cast<v8s*>(Hlo + (size_t)(b2+1)*WROW_ + kg*8) = plB;
    }
    ldsbar();

    // ---- MFMA gates+dec: D[20x32] = W · h^T, split-bf16 3 passes ----
    if (w < 4){
      const int mt = w >> 1, nt = w & 1;
      const int fr = (l & 15);
      const int fo = (l >> 4)*8;
      const u16* Ahi = Whi + (size_t)(mt*16 + fr)*WROW_ + fo;
      const u16* Alo = Wlo + (size_t)(mt*16 + fr)*WROW_ + fo;
      const u16* Bhi = Hhi + (size_t)(nt*16 + fr)*WROW_ + fo;
      const u16* Blo = Hlo + (size_t)(nt*16 + fr)*WROW_ + fo;
      v4f a0 = {0.f,0.f,0.f,0.f}, a1 = a0, a2 = a0;
      #pragma unroll
      for (int ks=0; ks<16; ks++){
        v8s wh = *reinterpret_cast<const v8s*>(Ahi + ks*32);
        v8s wl = *reinterpret_cast<const v8s*>(Alo + ks*32);
        v8s hh = *reinterpret_cast<const v8s*>(Bhi + ks*32);
        v8s hl = *reinterpret_cast<const v8s*>(Blo + ks*32);
        a0 = __builtin_amdgcn_mfma_f32_16x16x32_bf16(wh, hh, a0, 0, 0, 0);
        a1 = __builtin_amdgcn_mfma_f32_16x16x32_bf16(wh, hl, a1, 0, 0, 0);
        a2 = __builtin_amdgcn_mfma_f32_16x16x32_bf16(wl, hh, a2, 0, 0, 0);
      }
      v4f acc = a0 + a1 + a2;
      if (mt == 0){
        int col = nt*16 + fr;
        int r0w = (l >> 4)*4;
        #pragma unroll
        for (int q=0;q<4;q++) gv2[r0w + q][col] = acc[q];
      } else if ((l >> 4) == 0){
        int b = nt*16 + fr;
        float* dg = dec_g + (size_t)par*B_*A_ + (size_t)b*A_ + beta*4;
        unsigned long long p0 = ((unsigned long long)__float_as_uint(acc[1]) << 32) | __float_as_uint(acc[0]);
        unsigned long long p1 = ((unsigned long long)__float_as_uint(acc[3]) << 32) | __float_as_uint(acc[2]);
        AST(reinterpret_cast<unsigned long long*>(dg), p0);
        AST(reinterpret_cast<unsigned long long*>(dg + 2), p1);
      }
    }
    ldsbar();

    // ---- LSTM pointwise + publish h ----
    if (i < T_ && tid < 128){
      int hh = tid >> 5;
      int hidx = beta*4 + hh;
      const float* Gr = G2 + (size_t)i*65536 + (size_t)hidx*32 + b32;
      float gi = gv2[0*4+hh][b32] + Gr[0];
      float gf = gv2[1*4+hh][b32] + Gr[16384];
      float gz = gv2[2*4+hh][b32] + Gr[32768];
      float go = gv2[3*4+hh][b32] + Gr[49152];
      float co = c_l[tid];
      float cn = fsig(gf)*co + fsig(gi)*ftanh(gz);
      float hn = fsig(go)*ftanh(cn);
      c_l[tid] = cn;
      AST(h_gT + (size_t)(par^1)*16384 + (size_t)hidx*32 + b32, hn);
      catbuf[(size_t)(b32*T_ + i)*H3_ + H2_ + hidx] = hn;
    }
    gridbar2(bar, ++gen, grp);

    // ---- prefetch h_{i+1} (overlaps Y) ----
    if (i < T_){
      const unsigned long long* hp =
        reinterpret_cast<const unsigned long long*>(h_gT + (size_t)(par^1)*16384);
      #pragma unroll
      for (int kk=0;kk<8;kk++)
        hld[kk] = ALD(hp + (size_t)(kg*8 + kk)*16 + (b2 >> 1));
    }

    // ---- Y: scores_{i-1} for s-quarter sq of batch bb ----
    if (i > 0){
      const int r = bb*T_ + (i-1);
      if (tid < 512) dec_l[tid] = ALD(dec_g + (size_t)par*B_*A_ + (size_t)bb*A_ + tid);
      ldsbar();
      int a0i = l*8;
      float dec8[8];
      #pragma unroll
      for (int j=0;j<8;j++) dec8[j] = dec_l[a0i+j];
      #pragma unroll
      for (int it=0; it<7; ++it){
        int sl = w + it*16;
        if (sl < 100){
          int s = sq*100 + sl;
          float cv = cov_l[sl];
          uint4 e8 = *reinterpret_cast<const uint4*>(ep_bf + (size_t)(bb*S_ + s)*A_ + a0i);
          unsigned uu[4] = {e8.x, e8.y, e8.z, e8.w};
          float part = 0.f;
          #pragma unroll
          for (int j=0;j<4;j++){
            float xa = bf2f((u16)(uu[j] & 0xFFFFu)) + dec8[2*j]   + cv*wc8[2*j];
            part += va8[2*j]*ftanh(xa);
            float xb = bf2f((u16)(uu[j] >> 16))     + dec8[2*j+1] + cv*wc8[2*j+1];
            part += va8[2*j+1]*ftanh(xb);
          }
          part = wsum(part);
          if (l == 0){
            bool on = bytemode ? (m8p[bb*S_+s] != 0) : (m32p[bb*S_+s] != 0u);
            sc_l[sl] = on ? part : -1e9f;
          }
        }
      }
      __syncthreads();
      // local (m,Z); publish with gen tag in Z low mantissa bits
      if (tid < 64){
        float x1v = sc_l[l];
        float x2v = (l + 64 < 100) ? sc_l[l + 64] : -1e30f;
        float m = wmax(fmaxf(x1v, x2v));
        float z = __expf(x1v - m) + ((l + 64 < 100) ? __expf(x2v - m) : 0.f);
        z = wsum(z);
        if (l == 0){
          unsigned zt = (__float_as_uint(z) & ~255u) | (gen & 255u);
          unsigned long long pk = ((unsigned long long)zt << 32) | (unsigned long long)__float_as_uint(m);
          AST(mz + bb*4 + sq, pk);
        }
      }
      if (tid < 4){
        unsigned long long v;
        do {
          v = ALD(mz + bb*4 + tid);
          if (((unsigned)(v >> 32) & 255u) == (gen & 255u)) break;
          __builtin_amdgcn_s_sleep(1);
        } while (true);
        smz[tid][0] = __uint_as_float((unsigned)v);
        smz[tid][1] = __uint_as_float((unsigned)(v >> 32));
      }
      __syncthreads();
      float gm = fmaxf(fmaxf(smz[0][0], smz[1][0]), fmaxf(smz[2][0], smz[3][0]));
      float gZ = smz[0][1]*__expf(smz[0][0]-gm) + smz[1][1]*__expf(smz[1][0]-gm)
               + smz[2][1]*__expf(smz[2][0]-gm) + smz[3][1]*__expf(smz[3][0]-gm);
      float invZ = 1.f/gZ;
      if (tid < 100){
        float av = __expf(sc_l[tid] - gm)*invZ;
        int s = sq*100 + tid;
        float cn = cov_l[tid] + av;
        cov_l[tid] = cn;
        attns[(size_t)r*S_ + s] = av;
        covs[(size_t)r*S_ + s]  = cn;
      }
      __syncthreads();
    }

    // ---- unpack prefetched h for next iteration ----
    if (i < T_){
      #pragma unroll
      for (int kk=0;kk<8;kk++){
        hA[kk] = __uint_as_float((unsigned)hld[kk]);
        hB[kk] = __uint_as_float((unsigned)(hld[kk] >> 32));
      }
    }
  }
}

// ---------------- post-loop kernels ----------------

// context (deferred): catbuf[:, :1024] = attns @ enc   (fp32, single enc pass)
__global__ __launch_bounds__(256, 2) void k_ctx(
  const float* __restrict__ attns, const float* __restrict__ enc, float* __restrict__ catbuf)
{
  __shared__ float att_s[32][400];
  int d0 = blockIdx.x*64, b = blockIdx.y;
  int tid = threadIdx.x;
  for (int tt=0; tt<32; ++tt)
    for (int s = tid; s < S_; s += 256)
      att_s[tt][s] = attns[(size_t)(b*T_ + tt)*S_ + s];
  __syncthreads();
  int d = d0 + (tid & 63);
  int t0 = (tid >> 6)*8;
  float acc[8] = {0,0,0,0,0,0,0,0};
  const float* encb = enc + (size_t)b*S_*H2_ + d;
  #pragma unroll 4
  for (int s=0; s<S_; ++s){
    float ev = encb[(size_t)s*H2_];
    #pragma unroll
    for (int i=0;i<8;i++) acc[i] = __builtin_fmaf(att_s[t0+i][s], ev, acc[i]);
  }
  #pragma unroll
  for (int i=0;i<8;i++)
    catbuf[(size_t)(b*T_ + t0 + i)*H3_ + d] = acc[i];
}

// fp32 tiled GEMM: dec_states = tanh(catbuf @ W_ah + b_ah); optional bf16 copy
__global__ __launch_bounds__(256) void k_ahgemm(
  const float* __restrict__ Acat, const float* __restrict__ W_ah, const float* __restrict__ b_ah,
  float* __restrict__ dec_states, u16* __restrict__ ah_bf)
{
  __shared__ float Asf[32][68];
  __shared__ float Bsf[32][64];
  int n0 = blockIdx.x*64, m0 = blockIdx.y*64;
  int tid = threadIdx.x;
  int tx = tid & 15, ty = tid >> 4;
  float acc[4][4] = {};
  for (int kc = 0; kc < H3_; kc += 32){
    __syncthreads();
    #pragma unroll
    for (int i=0;i<8;i++){
      int e = i*256 + tid;
      Asf[e & 31][e >> 5] = Acat[(size_t)(m0 + (e >> 5))*H3_ + kc + (e & 31)];
    }
    #pragma unroll
    for (int i=0;i<8;i++){
      int e = i*256 + tid;
      Bsf[e >> 6][e & 63] = W_ah[(size_t)(kc + (e >> 6))*H_ + n0 + (e & 63)];
    }
    __syncthreads();
    #pragma unroll
    for (int k=0;k<32;k++){
      float4 a4 = *reinterpret_cast<const float4*>(&Asf[k][ty*4]);
      float4 b4 = *reinterpret_cast<const float4*>(&Bsf[k][tx*4]);
      float av[4] = {a4.x, a4.y, a4.z, a4.w};
      float bv[4] = {b4.x, b4.y, b4.z, b4.w};
      #pragma unroll
      for (int i=0;i<4;i++)
        #pragma unroll
        for (int j=0;j<4;j++)
          acc[i][j] = __builtin_fmaf(av[i], bv[j], acc[i][j]);
    }
  }
  #pragma unroll
  for (int i=0;i<4;i++){
    int rr = m0 + ty*4 + i;
    #pragma unroll
    for (int j=0;j<4;j++){
      int cc = n0 + tx*4 + j;
      float v = ftanh(acc[i][j] + b_ah[cc]);
      dec_states[(size_t)rr*H_ + cc] = v;
      if (ah_bf) ah_bf[(size_t)rr*H_ + cc] = f2bf(v);
    }
  }
}

__global__ __launch_bounds__(512) void k_pgen(const float* __restrict__ catbuf, const float* __restrict__ emb,
  const float* __restrict__ W_pg, const float* __restrict__ b_pg, float* __restrict__ pgens)
{
  int w = threadIdx.x >> 6, l = threadIdx.x & 63;
  int r = blockIdx.x*8 + w;
  float part = 0.0f;
  for (int d = l; d < PGK_; d += 64){
    float x = (d < H3_) ? catbuf[(size_t)r*H3_ + d] : emb[(size_t)r*E_ + (d - H3_)];
    part += x*W_pg[d];
  }
  part = wsum(part);
  if (l == 0) pgens[r] = fsig(part + b_pg[0]);
}

// per-row final: stats merge -> bitmask+hash scatter -> fast log transform
__global__ __launch_bounds__(512) void k_final2(
  float* __restrict__ logits, const float* __restrict__ pgens,
  const float* __restrict__ attns, const int* __restrict__ src,
  const float2* __restrict__ stats, int nblk)
{
  __shared__ unsigned bits[1568];
  __shared__ unsigned keys[1024];
  __shared__ float vals[1024];
  __shared__ float sred[18];
  int r = blockIdx.x;
  int b = r >> 5;
  int tid = threadIdx.x;
  int w = tid >> 6, l = tid & 63;
  float* row = logits + (size_t)r*V_;

  for (int i = tid; i < 1568; i += 512) bits[i] = 0u;
  for (int i = tid; i < 1024; i += 512){ keys[i] = 0xFFFFFFFFu; vals[i] = 0.0f; }

  if (stats){
    float m = -1e30f, Z = 0.0f;
    if (tid < nblk){ float2 st = stats[(size_t)r*nblk + tid]; m = st.x; Z = st.y; }
    #pragma unroll
    for (int off=32; off>0; off>>=1){
      float mo = __shfl_xor(m, off, 64);
      float Zo = __shfl_xor(Z, off, 64);
      float nm = fmaxf(m, mo);
      Z = Z*__expf(m - nm) + Zo*__expf(mo - nm);
      m = nm;
    }
    if (l == 0){ sred[w*2] = m; sred[w*2+1] = Z; }
    __syncthreads();
    if (tid == 0){
      float gm = -1e30f, gz = 0.0f;
      #pragma unroll
      for (int i=0;i<8;i++){
        float mi = sred[i*2], zi = sred[i*2+1];
        float nm = fmaxf(gm, mi);
        gz = gz*__expf(gm - nm) + zi*__expf(mi - nm);
        gm = nm;
      }
      sred[16] = gm; sred[17] = gz;
    }
    __syncthreads();
  } else {
    float m = -1e30f;
    for (int j = tid; j < V_/4; j += 512){
      float4 x = reinterpret_cast<const float4*>(row)[j];
      m = fmaxf(fmaxf(m, x.x), fmaxf(fmaxf(x.y, x.z), x.w));
    }
    m = wmax(m);
    if (l == 0) sred[w] = m;
    __syncthreads();
    if (tid == 0){
      float gm = -1e30f;
      #pragma unroll
      for (int i=0;i<8;i++) gm = fmaxf(gm, sred[i]);
      sred[16] = gm;
    }
    __syncthreads();
    float gm = sred[16];
    float z = 0.0f;
    for (int j = tid; j < V_/4; j += 512){
      float4 x = reinterpret_cast<const float4*>(row)[j];
      z += __expf(x.x-gm) + __expf(x.y-gm) + __expf(x.z-gm) + __expf(x.w-gm);
    }
    z = wsum(z);
    if (l == 0) sred[8 + w] = z;
    __syncthreads();
    if (tid == 0){
      float gz = 0.0f;
      #pragma unroll
      for (int i=0;i<8;i++) gz += sred[8 + i];
      sred[17] = gz;
    }
    __syncthreads();
  }

  float gm = sred[16];
  float gZ = sred[17];
  float pg = pgens[r];
  float scale = pg / gZ;
  float lscale = __logf(scale);

  if (tid < S_){
    int tok = src[b*S_ + tid];
    float add = (1.0f - pg)*attns[(size_t)r*S_ + tid];
    atomicOr(&bits[tok >> 5], 1u << (tok & 31));
    unsigned h = ((unsigned)tok * 2654435761u) >> 22;
    while (true){
      unsigned prev = atomicCAS(&keys[h], 0xFFFFFFFFu, (unsigned)tok);
      if (prev == 0xFFFFFFFFu || prev == (unsigned)tok){
        atomicAdd(&vals[h], add);
        break;
      }
      h = (h + 1) & 1023;
    }
  }
  __syncthreads();

  for (int j = tid; j < V_/4; j += 512){
    float4 x = reinterpret_cast<const float4*>(row)[j];
    int v = 4*j;
    float o[4];
    float xv[4] = {x.x, x.y, x.z, x.w};
    #pragma unroll
    for (int k=0;k<4;k++){
      int vv = v + k;
      bool hit = (bits[vv >> 5] >> (vv & 31)) & 1u;
      float tt = xv[k] - gm + lscale;
      if (!hit && tt > -25.0f){
        o[k] = tt;
      } else {
        float pval = __expf(xv[k] - gm)*scale;
        if (hit){
          unsigned h = ((unsigned)vv * 2654435761u) >> 22;
          while (keys[h] != 0xFFFFFFFFu){
            if (keys[h] == (unsigned)vv){ pval += vals[h]; break; }
            h = (h + 1) & 1023;
          }
        }
        o[k] = __logf(pval + 1e-20f);
      }
    }
    reinterpret_cast<float4*>(row)[j] = make_float4(o[0], o[1], o[2], o[3]);
  }
}

// ---------------- host ----------------

extern "C" void kernel_launch(void* const* d_in, const int* in_sizes, int n_in,
                              void* d_out, int out_size, void* d_ws, size_t ws_size,
                              hipStream_t stream)
{
  const int* src_tokens = (const int*)d_in[0];
  const float* embedded = (const float*)d_in[1];
  const float* enc      = (const float*)d_in[2];
  const void*  maskp    = (const void*)d_in[3];
  const float* h0  = (const float*)d_in[4];
  const float* c0  = (const float*)d_in[5];
  const float* W_ih = (const float*)d_in[6];
  const float* W_hh = (const float*)d_in[7];
  const float* b_ih = (const float*)d_in[8];
  const float* b_hh = (const float*)d_in[9];
  const float* W_enc = (const float*)d_in[10];
  const float* W_dec = (const float*)d_in[11];
  const float* w_cov = (const float*)d_in[12];
  const float* b_att = (const float*)d_in[13];
  const float* v_att = (const float*)d_in[14];
  const float* W_ah  = (const float*)d_in[15];
  const float* b_ah  = (const float*)d_in[16];
  const float* W_pg  = (const float*)d_in[17];
  const float* b_pg  = (const float*)d_in[18];
  const float* W_v   = (const float*)d_in[19];
  const float* b_v   = (const float*)d_in[20];
  (void)in_sizes; (void)n_in; (void)out_size;

  float* outp = (float*)d_out;
  float* logps = outp;                                  // (B,T,V)   204.8 MB
  float* dec_states = logps + (size_t)R_*V_;            // (B,T,H)
  float* attns = dec_states + (size_t)R_*H_;            // (B,T,S)
  float* covs  = attns + (size_t)R_*S_;                 // (B,T,S)
  float* pgens = covs + (size_t)R_*S_;                  // (B,T)

  // big transients live INSIDE the logps output region (dead until W_v GEMM)
  char* sp = (char*)logps;
  auto salloc = [&](size_t bytes) -> void* {
    void* p = (void*)sp;
    sp += (bytes + 255) & ~(size_t)255;
    return p;
  };
  unsigned* bar = (unsigned*)salloc(2048);
  unsigned long long* mz = (unsigned long long*)salloc((size_t)B_*4*8);
  u16* ep_bf    = (u16*)salloc((size_t)B_*S_*A_*2);        // 13.1 MB
  u16* enc3     = (u16*)salloc((size_t)B_*S_*3072*2);      // 78.6 MB
  u16* WencT3   = (u16*)salloc((size_t)A_*3072*2);         // 3.1 MB
  float* WihT   = (float*)salloc((size_t)E_*H4_*4);        // 1 MB
  float* W_decT = (float*)salloc((size_t)H_*A_*4);         // 1 MB
  float* G2     = (float*)salloc((size_t)R_*H4_*4);        // 8.4 MB [t][g][hidx][b]
  float* catbuf = (float*)salloc((size_t)R_*H3_*4);        // 6.3 MB [context | h]
  float* dec_g  = (float*)salloc((size_t)2*B_*A_*4);       // 128 KB double-buffered
  float* h_gT   = (float*)salloc((size_t)2*H_*B_*4);       // 128 KB double-buffered [k][b]
  // total ~112 MB < 204.8 MB -- all consumed before W_v GEMM writes logps

  // d_ws: only buffers live WHILE logps is being written
  char* wp = (char*)d_ws;
  auto walloc = [&](size_t bytes) -> void* {
    void* p = (void*)wp;
    wp += (bytes + 255) & ~(size_t)255;
    return p;
  };
  u16* ah_bf = (u16*)walloc((size_t)R_*H_*2);              // 1.05 MB
  u16* WvT   = (u16*)walloc((size_t)V_*H_*2);              // 51.2 MB
  float2* stats = (float2*)walloc((size_t)R_*NBLKV_*8);    // 3.2 MB
  const size_t ws_fast  = (size_t)R_*H_*2 + (size_t)V_*H_*2 + 512;
  const size_t ws_stats = ws_fast + (size_t)R_*NBLKV_*8 + 256;
  const bool fast_wv   = (ws_size >= ws_fast);
  const bool use_stats = (ws_size >= ws_stats);

  // setup
  k_init0<<<1, 512, 0, stream>>>(bar, mz);
  k_transpose<<<dim3(2,32), 256, 0, stream>>>(W_ih, WihT, H4_, E_);
  k_transpose<<<dim3(8,8), 256, 0, stream>>>(W_dec, W_decT, H_, A_);
  k_gih<<<128, 256, 0, stream>>>(embedded, WihT, b_ih, b_hh, G2);
  k_conv3<<<(B_*S_*H2_/4 + 255)/256, 256, 0, stream>>>(enc, enc3, B_*S_*H2_/4);
  k_convT3<<<dim3(8,16), 256, 0, stream>>>(W_enc, WencT3);
  if (fast_wv)
    k_convT<<<dim3((V_+63)/64, 8), 256, 0, stream>>>(W_v, WvT, H_, V_);

  // enc_proj: single split-bf16 GEMM (K=3072), bf16 output + b_att
  k_gemm_bf16<<<dim3(A_/128, (B_*S_)/128), 256, 0, stream>>>(
      enc3, 3072, WencT3, 3072, b_att, nullptr, ep_bf, A_, B_*S_, A_, 3072, nullptr, 0);

  // fused persistent recurrence (MFMA X-phase, 1024 threads)
  k_recur<<<GRB_, 1024, 0, stream>>>(W_hh, G2, W_decT, ep_bf, w_cov, v_att, maskp,
                                     h0, c0, h_gT, dec_g, mz,
                                     catbuf, attns, covs, bar);

  // deferred contexts + batched tail
  k_ctx<<<dim3(16, 32), 256, 0, stream>>>(attns, enc, catbuf);
  k_ahgemm<<<dim3(8,16), 256, 0, stream>>>(catbuf, W_ah, b_ah, dec_states, fast_wv ? ah_bf : (u16*)nullptr);
  k_pgen<<<128, 512, 0, stream>>>(catbuf, embedded, W_pg, b_pg, pgens);

  // logits
  if (fast_wv)
    k_gemm_bf16<<<dim3(NBLKV_, R_/128), 256, 0, stream>>>(
        ah_bf, H_, WvT, H_, b_v, logps, nullptr, V_, R_, V_, H_,
        use_stats ? stats : nullptr, NBLKV_);
  else
    k_wv_f32<<<dim3((V_+63)/64, R_/64), 256, 0, stream>>>(dec_states, W_v, b_v, logps);

  k_final2<<<R_, 512, 0, stream>>>(logps, pgens, attns, src_tokens,
                                   (fast_wv && use_stats) ? stats : nullptr, NBLKV_);
}